// Round 2
// baseline (1022.654 us; speedup 1.0000x reference)
//
#include <hip/hip_runtime.h>

#define Hd   128
#define Wd   128
#define HW   (Hd*Wd)
#define CIN  64
#define COUT 64
#define KK9  9
#define OCF  18   // offset channels = 2*K*K

// ---- repack weights for scalar-friendly (wave-uniform) access ----
// w_off: [18][64][3][3] -> w_off_t: [ci][kk][oc]  (oc contiguous, 18)
// w    : [64][64][3][3] -> w_t    : [kk][ci][co]  (co contiguous, 64)
__global__ __launch_bounds__(256) void repack_kernel(
    const float* __restrict__ w_off, const float* __restrict__ w,
    float* __restrict__ w_off_t, float* __restrict__ w_t) {
  int i = blockIdx.x * 256 + threadIdx.x;
  if (i < OCF * CIN * KK9) {
    int oc = i / (CIN * KK9);
    int r  = i - oc * (CIN * KK9);
    int ci = r / KK9;
    int kk = r - ci * KK9;
    w_off_t[(ci * KK9 + kk) * OCF + oc] = w_off[i];
  }
  if (i < COUT * CIN * KK9) {
    int co = i / (CIN * KK9);
    int r  = i - co * (CIN * KK9);
    int ci = r / KK9;
    int kk = r - ci * KK9;
    w_t[(kk * CIN + ci) * COUT + co] = w[i];
  }
}

// Fused deformable conv. Block = 128 threads = 2 waves over the SAME 64
// pixels (half a row). wave0 handles ci 0..31, wave1 ci 32..63; partials
// reduced through LDS. 2048 blocks -> 8 blocks/CU -> 4 waves/SIMD.
__global__ __launch_bounds__(128, 4) void deform_conv_fused(
    const float* __restrict__ x, const float* __restrict__ b_off,
    const float* __restrict__ w_off_t, const float* __restrict__ w_t,
    float* __restrict__ out) {
  __shared__ float pyx[OCF][64];    // phase A partial, then final py/px
  __shared__ float partA[16][64];   // co-chunk written by wave0
  __shared__ float partB[16][64];   // co-chunk written by wave1

  const int lane = threadIdx.x & 63;
  const int wv   = threadIdx.x >> 6;          // 0 or 1 (wave-uniform)
  const int plin = blockIdx.x * 64 + lane;
  const int wo = plin & (Wd - 1);
  const int ho = (plin >> 7) & (Hd - 1);
  const int b  = plin >> 14;
  const float* xb = x + (size_t)b * CIN * HW;
  const int ci0 = wv * 32;

  // integer 3x3 neighborhood for the offset conv
  int  offs[9];
  bool val[9];
#pragma unroll
  for (int kk = 0; kk < 9; ++kk) {
    int yy = ho - 1 + kk / 3;
    int xx = wo - 1 + kk % 3;
    val[kk]  = (yy >= 0) && (yy < Hd) && (xx >= 0) && (xx < Wd);
    offs[kk] = yy * Wd + xx;
  }

  // ---------- Phase A: offset conv partial over this wave's 32 ci ----------
  float accoff[OCF];
#pragma unroll
  for (int i = 0; i < OCF; ++i) accoff[i] = 0.f;

  {
    const float* xp = xb + ci0 * HW;
    float xv[9], xn[9];
#pragma unroll
    for (int kk = 0; kk < 9; ++kk) {
      xv[kk] = val[kk] ? xp[offs[kk]] : 0.f;
      xn[kk] = 0.f;
    }
    for (int ci = 0; ci < 32; ++ci) {
      const float* xq = xp + HW;
      if (ci < 31) {          // prefetch next ci's taps
#pragma unroll
        for (int kk = 0; kk < 9; ++kk) xn[kk] = val[kk] ? xq[offs[kk]] : 0.f;
      }
      const float* wp = w_off_t + (ci0 + ci) * (KK9 * OCF);
#pragma unroll
      for (int kk = 0; kk < 9; ++kk) {
#pragma unroll
        for (int oc = 0; oc < OCF; ++oc)
          accoff[oc] = fmaf(wp[kk * OCF + oc], xv[kk], accoff[oc]);
      }
#pragma unroll
      for (int kk = 0; kk < 9; ++kk) xv[kk] = xn[kk];
      xp = xq;
    }
  }

  // reduce the 18 partials across the 2 waves; wave0 finalizes py/px
  if (wv == 1) {
#pragma unroll
    for (int i = 0; i < OCF; ++i) pyx[i][lane] = accoff[i];
  }
  __syncthreads();
  if (wv == 0) {
#pragma unroll
    for (int kk = 0; kk < 9; ++kk) {
      float dy = accoff[2 * kk]     + pyx[2 * kk][lane]     + b_off[2 * kk];
      float dx = accoff[2 * kk + 1] + pyx[2 * kk + 1][lane] + b_off[2 * kk + 1];
      pyx[2 * kk][lane]     = (float)(ho - 1 + kk / 3) + dy;
      pyx[2 * kk + 1][lane] = (float)(wo - 1 + kk % 3) + dx;
    }
  }
  __syncthreads();

  // ---------- Phase B: bilinear sample + contraction over this wave's ci ----
  float acc[COUT];
#pragma unroll
  for (int i = 0; i < COUT; ++i) acc[i] = 0.f;

  for (int kk = 0; kk < 9; ++kk) {
    float py = pyx[2 * kk][lane];
    float px = pyx[2 * kk + 1][lane];
    float y0f = floorf(py), x0f = floorf(px);
    float wy1 = py - y0f, wy0 = 1.f - wy1;
    float wx1 = px - x0f, wx0 = 1.f - wx1;
    bool vy0 = (y0f >= 0.f)  && (y0f <  (float)Hd);
    bool vy1 = (y0f >= -1.f) && (y0f <  (float)(Hd - 1));
    bool vx0 = (x0f >= 0.f)  && (x0f <  (float)Wd);
    bool vx1 = (x0f >= -1.f) && (x0f <  (float)(Wd - 1));
    float w00 = wy0 * wx0 * ((vy0 && vx0) ? 1.f : 0.f);
    float w01 = wy0 * wx1 * ((vy0 && vx1) ? 1.f : 0.f);
    float w10 = wy1 * wx0 * ((vy1 && vx0) ? 1.f : 0.f);
    float w11 = wy1 * wx1 * ((vy1 && vx1) ? 1.f : 0.f);
    int y0 = (int)fminf(fmaxf(y0f, 0.f),       (float)(Hd - 1));
    int y1 = (int)fminf(fmaxf(y0f + 1.f, 0.f), (float)(Hd - 1));
    int x0 = (int)fminf(fmaxf(x0f, 0.f),       (float)(Wd - 1));
    int x1 = (int)fminf(fmaxf(x0f + 1.f, 0.f), (float)(Wd - 1));
    int o00 = y0 * Wd + x0, o01 = y0 * Wd + x1;
    int o10 = y1 * Wd + x0, o11 = y1 * Wd + x1;

    const float* xp = xb + ci0 * HW;
    const float* wpk = w_t + (kk * CIN + ci0) * COUT;
    float t00 = xp[o00], t01 = xp[o01], t10 = xp[o10], t11 = xp[o11];
    for (int ci = 0; ci < 32; ++ci) {
      float c00 = t00, c01 = t01, c10 = t10, c11 = t11;
      if (ci < 31) {          // prefetch next ci's 4 taps
        const float* xq = xp + HW;
        t00 = xq[o00]; t01 = xq[o01]; t10 = xq[o10]; t11 = xq[o11];
        xp = xq;
      }
      float v = w00 * c00;
      v = fmaf(w01, c01, v);
      v = fmaf(w10, c10, v);
      v = fmaf(w11, c11, v);
      const float* wp = wpk + ci * COUT;   // wave-uniform -> scalar loads
#pragma unroll
      for (int co = 0; co < COUT; ++co)
        acc[co] = fmaf(wp[co], v, acc[co]);
    }
  }

  // ---------- Phase C: cross-wave reduce + coalesced store ----------
  const size_t obase = (size_t)b * COUT * HW + (size_t)ho * Wd + wo;
#pragma unroll
  for (int r = 0; r < 2; ++r) {
    if (wv == 0) {
#pragma unroll
      for (int j = 0; j < 16; ++j) partA[j][lane] = acc[32 + r * 16 + j];
    } else {
#pragma unroll
      for (int j = 0; j < 16; ++j) partB[j][lane] = acc[r * 16 + j];
    }
    __syncthreads();
    if (wv == 0) {
#pragma unroll
      for (int j = 0; j < 16; ++j) {
        float s = acc[r * 16 + j] + partB[j][lane];
        out[obase + (size_t)(r * 16 + j) * HW] = s;
      }
    } else {
#pragma unroll
      for (int j = 0; j < 16; ++j) {
        float s = acc[32 + r * 16 + j] + partA[j][lane];
        out[obase + (size_t)(32 + r * 16 + j) * HW] = s;
      }
    }
    __syncthreads();
  }
}

extern "C" void kernel_launch(void* const* d_in, const int* in_sizes, int n_in,
                              void* d_out, int out_size, void* d_ws, size_t ws_size,
                              hipStream_t stream) {
  const float* x     = (const float*)d_in[0];
  const float* w_off = (const float*)d_in[1];
  const float* b_off = (const float*)d_in[2];
  const float* w     = (const float*)d_in[3];
  float* out = (float*)d_out;

  float* w_off_t = (float*)d_ws;            // 10368 floats (pad to 16384)
  float* w_t     = w_off_t + 16384;         // 36864 floats

  repack_kernel<<<(COUT * CIN * KK9 + 255) / 256, 256, 0, stream>>>(
      w_off, w, w_off_t, w_t);

  int nblocks = (8 * Hd * Wd) / 64;         // 2048 blocks of 128 threads
  deform_conv_fused<<<nblocks, 128, 0, stream>>>(
      x, b_off, w_off_t, w_t, out);
}

// Round 3
// 260.518 us; speedup vs baseline: 3.9255x; 3.9255x over previous
//
#include <hip/hip_runtime.h>

typedef float  v4f __attribute__((ext_vector_type(4)));
typedef short  v8s __attribute__((ext_vector_type(8)));

#define Hd   128
#define Wd   128
#define HW   (Hd*Wd)
#define CIN  64
#define COUT 64

// round-to-nearest-even fp32 -> bf16 (as ushort)
__device__ __forceinline__ uint f2bf_rn(float v) {
  uint u = __builtin_bit_cast(uint, v);
  u += 0x7FFFu + ((u >> 16) & 1u);
  return u >> 16;
}

// split fp32 into bf16 hi (RN) + bf16 lo (RTZ of residual)
__device__ __forceinline__ void split_bf(float v, uint& h, uint& l) {
  uint u = __builtin_bit_cast(uint, v);
  uint r = u + 0x7FFFu + ((u >> 16) & 1u);
  h = r >> 16;
  float hf = __builtin_bit_cast(float, (r >> 16) << 16);
  float lf = v - hf;
  l = __builtin_bit_cast(uint, lf) >> 16;
}

// ---- repack weights ----
// w    [64co][64ci][3][3] -> whi/wlo [co][k]   (k = kk*64+ci, contiguous)
// w_off[18oc][64ci][3][3] -> woff_t  [32][k]   (single bf16, rows 18..31 = 0)
__global__ __launch_bounds__(256) void repack(
    const float* __restrict__ w_off, const float* __restrict__ w,
    ushort* __restrict__ woff_t, ushort* __restrict__ whi,
    ushort* __restrict__ wlo) {
  int i = blockIdx.x * 256 + threadIdx.x;        // 0..36863 (=64*576)
  int co = i / 576, k = i - co * 576;
  int kk = k >> 6, ci = k & 63;
  float wv = w[(co * 64 + ci) * 9 + kk];
  uint h, l;
  split_bf(wv, h, l);
  whi[i] = (ushort)h;
  wlo[i] = (ushort)l;
  if (i < 32 * 576) {
    float v = (co < 18) ? w_off[(co * 64 + ci) * 9 + kk] : 0.f;
    woff_t[i] = (ushort)f2bf_rn(v);
  }
}

// Fused deformable conv: one block = 64 pixels (half-row) x all 64 co.
// Phase A: im2col (integer taps, bf16) -> MFMA offset conv (18 ch).
// Phase B: per kk: fp32 bilinear blend -> bf16 hi/lo tile -> 3x split-bf16 MFMA.
__global__ __launch_bounds__(256, 4) void dconv(
    const float* __restrict__ x, const float* __restrict__ b_off,
    const ushort* __restrict__ woff_t, const ushort* __restrict__ whi,
    const ushort* __restrict__ wlo, float* __restrict__ out) {

  __shared__ uint4 colsA[64 * 8];   // hi tile (and phase-A im2col), 8KB
  __shared__ uint4 colsB[64 * 8];   // lo tile, 8KB
  __shared__ float pypx[18][64];    // dy/dx (+bias) per kk-channel, 4.5KB

  const int t    = threadIdx.x;
  const int lane = t & 63;
  const int wv   = t >> 6;                       // wave id 0..3
  const int lo16 = lane & 15, hi2 = lane >> 4;

  // XCD swizzle: 2048 blocks, 8 XCDs -> each XCD owns one batch image
  const int wid = ((blockIdx.x & 7) << 8) | (blockIdx.x >> 3);
  const int b   = wid >> 8;
  const int ho  = (wid >> 1) & 127;
  const int wo0 = (wid & 1) << 6;

  const int px = t & 63;                         // staging pixel
  const int g  = t >> 6;                         // staging ci-group (16 ci)
  const float* xb = x + (size_t)b * (CIN * HW);

  // ---------------- phase A: offset conv (MFMA, single bf16) ----------------
  v4f oacc0 = {0.f, 0.f, 0.f, 0.f};
  v4f oacc1 = {0.f, 0.f, 0.f, 0.f};

  for (int kk = 0; kk < 9; ++kk) {
    if (kk) __syncthreads();
    {
      int yy = ho - 1 + kk / 3;
      int xx = wo0 + px - 1 + kk % 3;
      bool vok = (yy >= 0) && (yy < Hd) && (xx >= 0) && (xx < Wd);
      const float* xp = xb + (size_t)(g * 16) * HW + yy * Wd + xx;
      uint pk[8];
#pragma unroll
      for (int u = 0; u < 16; u += 2) {
        float a0 = vok ? xp[(u + 0) * HW] : 0.f;
        float a1 = vok ? xp[(u + 1) * HW] : 0.f;
        pk[u >> 1] = f2bf_rn(a0) | (f2bf_rn(a1) << 16);
      }
      uint4 q0 = {pk[0], pk[1], pk[2], pk[3]};
      uint4 q1 = {pk[4], pk[5], pk[6], pk[7]};
      int base = px * 8, s = px & 7;
      colsA[base + ((g * 2 + 0) ^ s)] = q0;
      colsA[base + ((g * 2 + 1) ^ s)] = q1;
    }
    __syncthreads();
    int pxr = wv * 16 + lo16;
#pragma unroll
    for (int kst = 0; kst < 2; ++kst) {
      const v8s* ap0 = (const v8s*)(woff_t + (0  + lo16) * 576 + kk * 64 + kst * 32 + hi2 * 8);
      const v8s* ap1 = (const v8s*)(woff_t + (16 + lo16) * 576 + kk * 64 + kst * 32 + hi2 * 8);
      const v8s* bp  = (const v8s*)&colsA[pxr * 8 + ((kst * 4 + hi2) ^ (pxr & 7))];
      v8s bfr = *bp;
      oacc0 = __builtin_amdgcn_mfma_f32_16x16x32_bf16(*ap0, bfr, oacc0, 0, 0, 0);
      oacc1 = __builtin_amdgcn_mfma_f32_16x16x32_bf16(*ap1, bfr, oacc1, 0, 0, 0);
    }
  }
  // scatter dy/dx (+bias) to LDS: C layout col=lane&15, row=(lane>>4)*4+j
  {
    int pxw = wv * 16 + lo16;
#pragma unroll
    for (int j = 0; j < 4; ++j) {
      int oc = hi2 * 4 + j;
      pypx[oc][pxw] = oacc0[j] + b_off[oc];
    }
    if (hi2 == 0) {
#pragma unroll
      for (int j = 0; j < 2; ++j)
        pypx[16 + j][pxw] = oacc1[j] + b_off[16 + j];
    }
  }
  __syncthreads();

  // ---------------- phase B: blend + split-bf16 main GEMM ----------------
  v4f acc[2][2];
#pragma unroll
  for (int a = 0; a < 2; ++a)
#pragma unroll
    for (int c = 0; c < 2; ++c) acc[a][c] = (v4f){0.f, 0.f, 0.f, 0.f};

  const int co0 = (wv & 1) << 5;
  const int px0 = (wv >> 1) << 5;

  for (int kk = 0; kk < 9; ++kk) {
    if (kk) __syncthreads();
    {
      float dy = pypx[2 * kk][px], dx = pypx[2 * kk + 1][px];
      float py  = (float)(ho - 1 + kk / 3) + dy;
      float pxf = (float)(wo0 + px - 1 + kk % 3) + dx;
      float y0f = floorf(py), x0f = floorf(pxf);
      float wy1 = py - y0f,  wy0 = 1.f - wy1;
      float wx1 = pxf - x0f, wx0 = 1.f - wx1;
      bool vy0 = (y0f >= 0.f)  && (y0f < (float)Hd);
      bool vy1 = (y0f >= -1.f) && (y0f < (float)(Hd - 1));
      bool vx0 = (x0f >= 0.f)  && (x0f < (float)Wd);
      bool vx1 = (x0f >= -1.f) && (x0f < (float)(Wd - 1));
      float w00 = wy0 * wx0 * ((vy0 && vx0) ? 1.f : 0.f);
      float w01 = wy0 * wx1 * ((vy0 && vx1) ? 1.f : 0.f);
      float w10 = wy1 * wx0 * ((vy1 && vx0) ? 1.f : 0.f);
      float w11 = wy1 * wx1 * ((vy1 && vx1) ? 1.f : 0.f);
      int y0  = (int)fminf(fmaxf(y0f,       0.f), (float)(Hd - 1));
      int y1  = (int)fminf(fmaxf(y0f + 1.f, 0.f), (float)(Hd - 1));
      int x0i = (int)fminf(fmaxf(x0f,       0.f), (float)(Wd - 1));
      int x1i = (int)fminf(fmaxf(x0f + 1.f, 0.f), (float)(Wd - 1));
      const float* xp  = xb + (size_t)(g * 16) * HW;
      const float* p00 = xp + y0 * Wd + x0i;
      const float* p01 = xp + y0 * Wd + x1i;
      const float* p10 = xp + y1 * Wd + x0i;
      const float* p11 = xp + y1 * Wd + x1i;
      uint ph[8], pl[8];
#pragma unroll
      for (int u = 0; u < 16; u += 2) {
        float v0 = w00 * p00[u * HW] + w01 * p01[u * HW] +
                   w10 * p10[u * HW] + w11 * p11[u * HW];
        float v1 = w00 * p00[(u + 1) * HW] + w01 * p01[(u + 1) * HW] +
                   w10 * p10[(u + 1) * HW] + w11 * p11[(u + 1) * HW];
        uint h0, l0, h1, l1;
        split_bf(v0, h0, l0);
        split_bf(v1, h1, l1);
        ph[u >> 1] = h0 | (h1 << 16);
        pl[u >> 1] = l0 | (l1 << 16);
      }
      uint4 qh0 = {ph[0], ph[1], ph[2], ph[3]};
      uint4 qh1 = {ph[4], ph[5], ph[6], ph[7]};
      uint4 ql0 = {pl[0], pl[1], pl[2], pl[3]};
      uint4 ql1 = {pl[4], pl[5], pl[6], pl[7]};
      int base = px * 8, s = px & 7;
      colsA[base + ((g * 2 + 0) ^ s)] = qh0;
      colsA[base + ((g * 2 + 1) ^ s)] = qh1;
      colsB[base + ((g * 2 + 0) ^ s)] = ql0;
      colsB[base + ((g * 2 + 1) ^ s)] = ql1;
    }
    __syncthreads();

#pragma unroll
    for (int kst = 0; kst < 2; ++kst) {
      const int ko = kk * 64 + kst * 32 + hi2 * 8;
      v8s ah0 = *(const v8s*)(whi + (co0 +      lo16) * 576 + ko);
      v8s ah1 = *(const v8s*)(whi + (co0 + 16 + lo16) * 576 + ko);
      v8s al0 = *(const v8s*)(wlo + (co0 +      lo16) * 576 + ko);
      v8s al1 = *(const v8s*)(wlo + (co0 + 16 + lo16) * 576 + ko);
      int pr0 = px0 + lo16, pr1 = px0 + 16 + lo16;
      int k4 = kst * 4 + hi2;
      v8s bh0 = *(const v8s*)&colsA[pr0 * 8 + (k4 ^ (pr0 & 7))];
      v8s bh1 = *(const v8s*)&colsA[pr1 * 8 + (k4 ^ (pr1 & 7))];
      v8s bl0 = *(const v8s*)&colsB[pr0 * 8 + (k4 ^ (pr0 & 7))];
      v8s bl1 = *(const v8s*)&colsB[pr1 * 8 + (k4 ^ (pr1 & 7))];

      acc[0][0] = __builtin_amdgcn_mfma_f32_16x16x32_bf16(ah0, bh0, acc[0][0], 0, 0, 0);
      acc[0][0] = __builtin_amdgcn_mfma_f32_16x16x32_bf16(ah0, bl0, acc[0][0], 0, 0, 0);
      acc[0][0] = __builtin_amdgcn_mfma_f32_16x16x32_bf16(al0, bh0, acc[0][0], 0, 0, 0);

      acc[0][1] = __builtin_amdgcn_mfma_f32_16x16x32_bf16(ah0, bh1, acc[0][1], 0, 0, 0);
      acc[0][1] = __builtin_amdgcn_mfma_f32_16x16x32_bf16(ah0, bl1, acc[0][1], 0, 0, 0);
      acc[0][1] = __builtin_amdgcn_mfma_f32_16x16x32_bf16(al0, bh1, acc[0][1], 0, 0, 0);

      acc[1][0] = __builtin_amdgcn_mfma_f32_16x16x32_bf16(ah1, bh0, acc[1][0], 0, 0, 0);
      acc[1][0] = __builtin_amdgcn_mfma_f32_16x16x32_bf16(ah1, bl0, acc[1][0], 0, 0, 0);
      acc[1][0] = __builtin_amdgcn_mfma_f32_16x16x32_bf16(al1, bh0, acc[1][0], 0, 0, 0);

      acc[1][1] = __builtin_amdgcn_mfma_f32_16x16x32_bf16(ah1, bh1, acc[1][1], 0, 0, 0);
      acc[1][1] = __builtin_amdgcn_mfma_f32_16x16x32_bf16(ah1, bl1, acc[1][1], 0, 0, 0);
      acc[1][1] = __builtin_amdgcn_mfma_f32_16x16x32_bf16(al1, bh1, acc[1][1], 0, 0, 0);
    }
  }

  // ---------------- epilogue: store ----------------
  const int wo_b = wo0 + px0 + lo16;
#pragma unroll
  for (int ct = 0; ct < 2; ++ct) {
#pragma unroll
    for (int pt = 0; pt < 2; ++pt) {
#pragma unroll
      for (int j = 0; j < 4; ++j) {
        int co = co0 + ct * 16 + hi2 * 4 + j;
        out[(((size_t)b * COUT + co) * Hd + ho) * Wd + wo_b + pt * 16] = acc[ct][pt][j];
      }
    }
  }
}

extern "C" void kernel_launch(void* const* d_in, const int* in_sizes, int n_in,
                              void* d_out, int out_size, void* d_ws, size_t ws_size,
                              hipStream_t stream) {
  const float* x     = (const float*)d_in[0];
  const float* w_off = (const float*)d_in[1];
  const float* b_off = (const float*)d_in[2];
  const float* w     = (const float*)d_in[3];
  float* out = (float*)d_out;

  ushort* woff_t = (ushort*)d_ws;              // 32*576
  ushort* whi    = woff_t + 32 * 576;          // 64*576
  ushort* wlo    = whi + 64 * 576;             // 64*576  (total 184,320 B)

  repack<<<144, 256, 0, stream>>>(w_off, w, woff_t, whi, wlo);
  dconv<<<2048, 256, 0, stream>>>(x, b_off, woff_t, whi, wlo, out);
}

// Round 5
// 191.709 us; speedup vs baseline: 5.3344x; 1.3589x over previous
//
#include <hip/hip_runtime.h>

typedef float  v4f __attribute__((ext_vector_type(4)));
typedef short  v8s __attribute__((ext_vector_type(8)));
typedef uint   v4u __attribute__((ext_vector_type(4)));

#define Hd   128
#define Wd   128
#define HW   (Hd*Wd)
#define CIN  64
#define COUT 64

// round-to-nearest-even fp32 -> bf16 (as ushort in low bits)
__device__ __forceinline__ uint f2bf_rn(float v) {
  uint u = __builtin_bit_cast(uint, v);
  u += 0x7FFFu + ((u >> 16) & 1u);
  return u >> 16;
}

// split fp32 into bf16 hi (RN) + bf16 lo (residual)
__device__ __forceinline__ void split_bf(float v, uint& h, uint& l) {
  uint u = __builtin_bit_cast(uint, v);
  uint r = u + 0x7FFFu + ((u >> 16) & 1u);
  h = r >> 16;
  float hf = __builtin_bit_cast(float, (r >> 16) << 16);
  float lf = v - hf;
  l = __builtin_bit_cast(uint, lf) >> 16;
}

// ---- repack weights ----
__global__ __launch_bounds__(256) void repack(
    const float* __restrict__ w_off, const float* __restrict__ w,
    ushort* __restrict__ woff_t, ushort* __restrict__ whi,
    ushort* __restrict__ wlo) {
  int i = blockIdx.x * 256 + threadIdx.x;        // 0..36863 (=64*576)
  int co = i / 576, k = i - co * 576;
  int kk = k >> 6, ci = k & 63;
  float wv = w[(co * 64 + ci) * 9 + kk];
  uint h, l;
  split_bf(wv, h, l);
  whi[i] = (ushort)h;
  wlo[i] = (ushort)l;
  if (i < 32 * 576) {
    float v = (co < 18) ? w_off[(co * 64 + ci) * 9 + kk] : 0.f;
    woff_t[i] = (ushort)f2bf_rn(v);
  }
}

// ---- NCHW fp32 -> NHWC bf16 transpose ----
__global__ __launch_bounds__(256) void transpose_nhwc(
    const float* __restrict__ x, ushort* __restrict__ x_t) {
  __shared__ ushort tile[128][72];   // stride 144B = 9*16B, rows 16B-aligned
  const int t  = threadIdx.x;
  const int by = blockIdx.x;                     // b*128 + y
  const float* xp = x + (size_t)(by >> 7) * (CIN * HW) + (size_t)(by & 127) * Wd;
#pragma unroll
  for (int r = 0; r < 32; ++r) {
    int idx = r * 256 + t;
    int ci = idx >> 7, xw = idx & 127;
    tile[xw][ci] = (ushort)f2bf_rn(xp[(size_t)ci * HW + xw]);
  }
  __syncthreads();
  ushort* op = x_t + (size_t)by * (Wd * CIN);
#pragma unroll
  for (int r = 0; r < 4; ++r) {
    int c = r * 256 + t;
    int xw = c >> 3, q = c & 7;
    v4u v = *(const v4u*)&tile[xw][q * 8];
    *(v4u*)(op + xw * 64 + q * 8) = v;
  }
}

// ======= round-3 structure, NHWC bf16 gather source (minimal delta) =======
__global__ __launch_bounds__(256, 4) void dconv_nhwc2(
    const ushort* __restrict__ x_t, const float* __restrict__ b_off,
    const ushort* __restrict__ woff_t, const ushort* __restrict__ whi,
    const ushort* __restrict__ wlo, float* __restrict__ out) {

  __shared__ v4u  colsA[64 * 8];
  __shared__ v4u  colsB[64 * 8];
  __shared__ float pypx[18][64];

  const int t    = threadIdx.x;
  const int lane = t & 63;
  const int wv   = t >> 6;
  const int lo16 = lane & 15, hi2 = lane >> 4;
  const int wid = ((blockIdx.x & 7) << 8) | (blockIdx.x >> 3);
  const int b   = wid >> 8;
  const int ho  = (wid >> 1) & 127;
  const int wo0 = (wid & 1) << 6;
  const int px = t & 63;
  const int g  = t >> 6;
  const ushort* xtb = x_t + (size_t)b * (HW * CIN);

  // ---------------- phase A: offset conv (per-kk stage -> MFMA) -----------
  v4f oacc0 = {0.f, 0.f, 0.f, 0.f};
  v4f oacc1 = {0.f, 0.f, 0.f, 0.f};

  for (int kk = 0; kk < 9; ++kk) {
    if (kk) __syncthreads();
    {
      int yy = ho - 1 + kk / 3;
      int xx = wo0 + px - 1 + kk % 3;
      bool vok = (yy >= 0) && (yy < Hd) && (xx >= 0) && (xx < Wd);
      v4u q0 = {0u, 0u, 0u, 0u}, q1 = {0u, 0u, 0u, 0u};
      if (vok) {
        const ushort* p = xtb + ((yy << 7) + xx) * 64 + g * 16;
        q0 = *(const v4u*)p;
        q1 = *(const v4u*)(p + 8);
      }
      int base = px * 8, s = px & 7;
      colsA[base + ((g * 2 + 0) ^ s)] = q0;
      colsA[base + ((g * 2 + 1) ^ s)] = q1;
    }
    __syncthreads();
    int pxr = wv * 16 + lo16;
#pragma unroll
    for (int kst = 0; kst < 2; ++kst) {
      const v8s* ap0 = (const v8s*)(woff_t + (0  + lo16) * 576 + kk * 64 + kst * 32 + hi2 * 8);
      const v8s* ap1 = (const v8s*)(woff_t + (16 + lo16) * 576 + kk * 64 + kst * 32 + hi2 * 8);
      const v8s* bp  = (const v8s*)&colsA[pxr * 8 + ((kst * 4 + hi2) ^ (pxr & 7))];
      v8s bfr = *bp;
      oacc0 = __builtin_amdgcn_mfma_f32_16x16x32_bf16(*ap0, bfr, oacc0, 0, 0, 0);
      oacc1 = __builtin_amdgcn_mfma_f32_16x16x32_bf16(*ap1, bfr, oacc1, 0, 0, 0);
    }
  }
  {
    int pxw = wv * 16 + lo16;
#pragma unroll
    for (int j = 0; j < 4; ++j) {
      int oc = hi2 * 4 + j;
      pypx[oc][pxw] = oacc0[j] + b_off[oc];
    }
    if (hi2 == 0) {
#pragma unroll
      for (int j = 0; j < 2; ++j)
        pypx[16 + j][pxw] = oacc1[j] + b_off[16 + j];
    }
  }
  __syncthreads();

  // ---------------- phase B: per-kk blend -> split hi/lo -> MFMA ----------
  v4f acc[2][2];
#pragma unroll
  for (int a = 0; a < 2; ++a)
#pragma unroll
    for (int c = 0; c < 2; ++c) acc[a][c] = (v4f){0.f, 0.f, 0.f, 0.f};

  const int co0 = (wv & 1) << 5;
  const int px0 = (wv >> 1) << 5;

  for (int kk = 0; kk < 9; ++kk) {
    if (kk) __syncthreads();
    {
      float dy = pypx[2 * kk][px], dxo = pypx[2 * kk + 1][px];
      float py  = (float)(ho - 1 + kk / 3) + dy;
      float pxf = (float)(wo0 + px - 1 + kk % 3) + dxo;
      float y0f = floorf(py), x0f = floorf(pxf);
      float wy1 = py - y0f,  wy0 = 1.f - wy1;
      float wx1 = pxf - x0f, wx0 = 1.f - wx1;
      bool vy0 = (y0f >= 0.f)  && (y0f < 128.f);
      bool vy1 = (y0f >= -1.f) && (y0f < 127.f);
      bool vx0 = (x0f >= 0.f)  && (x0f < 128.f);
      bool vx1 = (x0f >= -1.f) && (x0f < 127.f);
      float w00 = wy0 * wx0 * ((vy0 && vx0) ? 1.f : 0.f);
      float w01 = wy0 * wx1 * ((vy0 && vx1) ? 1.f : 0.f);
      float w10 = wy1 * wx0 * ((vy1 && vx0) ? 1.f : 0.f);
      float w11 = wy1 * wx1 * ((vy1 && vx1) ? 1.f : 0.f);
      int y0  = (int)fminf(fmaxf(y0f,       0.f), 127.f);
      int y1  = (int)fminf(fmaxf(y0f + 1.f, 0.f), 127.f);
      int x0i = (int)fminf(fmaxf(x0f,       0.f), 127.f);
      int x1i = (int)fminf(fmaxf(x0f + 1.f, 0.f), 127.f);
      int o00 = ((y0 << 7) + x0i) * 64 + g * 16;
      int o01 = ((y0 << 7) + x1i) * 64 + g * 16;
      int o10 = ((y1 << 7) + x0i) * 64 + g * 16;
      int o11 = ((y1 << 7) + x1i) * 64 + g * 16;
      v4u g00a = *(const v4u*)(xtb + o00), g00b = *(const v4u*)(xtb + o00 + 8);
      v4u g01a = *(const v4u*)(xtb + o01), g01b = *(const v4u*)(xtb + o01 + 8);
      v4u g10a = *(const v4u*)(xtb + o10), g10b = *(const v4u*)(xtb + o10 + 8);
      v4u g11a = *(const v4u*)(xtb + o11), g11b = *(const v4u*)(xtb + o11 + 8);

      uint ph[8], pl[8];
#pragma unroll
      for (int j = 0; j < 8; ++j) {
        uint u00 = (j < 4) ? g00a[j] : g00b[j - 4];
        uint u01 = (j < 4) ? g01a[j] : g01b[j - 4];
        uint u10 = (j < 4) ? g10a[j] : g10b[j - 4];
        uint u11 = (j < 4) ? g11a[j] : g11b[j - 4];
        float a0 = __builtin_bit_cast(float, u00 << 16);
        float a1 = __builtin_bit_cast(float, u01 << 16);
        float a2 = __builtin_bit_cast(float, u10 << 16);
        float a3 = __builtin_bit_cast(float, u11 << 16);
        float v0 = w00 * a0; v0 = fmaf(w01, a1, v0);
        v0 = fmaf(w10, a2, v0); v0 = fmaf(w11, a3, v0);
        float h0 = __builtin_bit_cast(float, u00 & 0xFFFF0000u);
        float h1 = __builtin_bit_cast(float, u01 & 0xFFFF0000u);
        float h2 = __builtin_bit_cast(float, u10 & 0xFFFF0000u);
        float h3 = __builtin_bit_cast(float, u11 & 0xFFFF0000u);
        float v1 = w00 * h0; v1 = fmaf(w01, h1, v1);
        v1 = fmaf(w10, h2, v1); v1 = fmaf(w11, h3, v1);
        uint hh0, ll0, hh1, ll1;
        split_bf(v0, hh0, ll0);
        split_bf(v1, hh1, ll1);
        ph[j] = hh0 | (hh1 << 16);
        pl[j] = ll0 | (ll1 << 16);
      }
      v4u qh0 = {ph[0], ph[1], ph[2], ph[3]};
      v4u qh1 = {ph[4], ph[5], ph[6], ph[7]};
      v4u ql0 = {pl[0], pl[1], pl[2], pl[3]};
      v4u ql1 = {pl[4], pl[5], pl[6], pl[7]};
      int base = px * 8, s = px & 7;
      colsA[base + ((g * 2 + 0) ^ s)] = qh0;
      colsA[base + ((g * 2 + 1) ^ s)] = qh1;
      colsB[base + ((g * 2 + 0) ^ s)] = ql0;
      colsB[base + ((g * 2 + 1) ^ s)] = ql1;
    }
    __syncthreads();

#pragma unroll
    for (int kst = 0; kst < 2; ++kst) {
      const int ko = kk * 64 + kst * 32 + hi2 * 8;
      v8s ah0 = *(const v8s*)(whi + (co0 +      lo16) * 576 + ko);
      v8s ah1 = *(const v8s*)(whi + (co0 + 16 + lo16) * 576 + ko);
      v8s al0 = *(const v8s*)(wlo + (co0 +      lo16) * 576 + ko);
      v8s al1 = *(const v8s*)(wlo + (co0 + 16 + lo16) * 576 + ko);
      int pr0 = px0 + lo16, pr1 = px0 + 16 + lo16;
      int k4 = kst * 4 + hi2;
      v8s bh0 = *(const v8s*)&colsA[pr0 * 8 + (k4 ^ (pr0 & 7))];
      v8s bh1 = *(const v8s*)&colsA[pr1 * 8 + (k4 ^ (pr1 & 7))];
      v8s bl0 = *(const v8s*)&colsB[pr0 * 8 + (k4 ^ (pr0 & 7))];
      v8s bl1 = *(const v8s*)&colsB[pr1 * 8 + (k4 ^ (pr1 & 7))];

      acc[0][0] = __builtin_amdgcn_mfma_f32_16x16x32_bf16(ah0, bh0, acc[0][0], 0, 0, 0);
      acc[0][0] = __builtin_amdgcn_mfma_f32_16x16x32_bf16(ah0, bl0, acc[0][0], 0, 0, 0);
      acc[0][0] = __builtin_amdgcn_mfma_f32_16x16x32_bf16(al0, bh0, acc[0][0], 0, 0, 0);
      acc[0][1] = __builtin_amdgcn_mfma_f32_16x16x32_bf16(ah0, bh1, acc[0][1], 0, 0, 0);
      acc[0][1] = __builtin_amdgcn_mfma_f32_16x16x32_bf16(ah0, bl1, acc[0][1], 0, 0, 0);
      acc[0][1] = __builtin_amdgcn_mfma_f32_16x16x32_bf16(al0, bh1, acc[0][1], 0, 0, 0);
      acc[1][0] = __builtin_amdgcn_mfma_f32_16x16x32_bf16(ah1, bh0, acc[1][0], 0, 0, 0);
      acc[1][0] = __builtin_amdgcn_mfma_f32_16x16x32_bf16(ah1, bl0, acc[1][0], 0, 0, 0);
      acc[1][0] = __builtin_amdgcn_mfma_f32_16x16x32_bf16(al1, bh0, acc[1][0], 0, 0, 0);
      acc[1][1] = __builtin_amdgcn_mfma_f32_16x16x32_bf16(ah1, bh1, acc[1][1], 0, 0, 0);
      acc[1][1] = __builtin_amdgcn_mfma_f32_16x16x32_bf16(ah1, bl1, acc[1][1], 0, 0, 0);
      acc[1][1] = __builtin_amdgcn_mfma_f32_16x16x32_bf16(al1, bh1, acc[1][1], 0, 0, 0);
    }
  }

  // ---------------- epilogue ----------------
  const int wo_b = wo0 + px0 + lo16;
#pragma unroll
  for (int ct = 0; ct < 2; ++ct) {
#pragma unroll
    for (int pt = 0; pt < 2; ++pt) {
#pragma unroll
      for (int j = 0; j < 4; ++j) {
        int co = co0 + ct * 16 + hi2 * 4 + j;
        out[(((size_t)b * COUT + co) * Hd + ho) * Wd + wo_b + pt * 16] = acc[ct][pt][j];
      }
    }
  }
}

// =================== fallback (round-3 kernel, NCHW fp32 gathers) ==========
__global__ __launch_bounds__(256, 4) void dconv_old(
    const float* __restrict__ x, const float* __restrict__ b_off,
    const ushort* __restrict__ woff_t, const ushort* __restrict__ whi,
    const ushort* __restrict__ wlo, float* __restrict__ out) {

  __shared__ uint4 colsA[64 * 8];
  __shared__ uint4 colsB[64 * 8];
  __shared__ float pypx[18][64];

  const int t    = threadIdx.x;
  const int lane = t & 63;
  const int wv   = t >> 6;
  const int lo16 = lane & 15, hi2 = lane >> 4;
  const int wid = ((blockIdx.x & 7) << 8) | (blockIdx.x >> 3);
  const int b   = wid >> 8;
  const int ho  = (wid >> 1) & 127;
  const int wo0 = (wid & 1) << 6;
  const int px = t & 63;
  const int g  = t >> 6;
  const float* xb = x + (size_t)b * (CIN * HW);

  v4f oacc0 = {0.f, 0.f, 0.f, 0.f};
  v4f oacc1 = {0.f, 0.f, 0.f, 0.f};

  for (int kk = 0; kk < 9; ++kk) {
    if (kk) __syncthreads();
    {
      int yy = ho - 1 + kk / 3;
      int xx = wo0 + px - 1 + kk % 3;
      bool vok = (yy >= 0) && (yy < Hd) && (xx >= 0) && (xx < Wd);
      const float* xp = xb + (size_t)(g * 16) * HW + yy * Wd + xx;
      uint pk[8];
#pragma unroll
      for (int u = 0; u < 16; u += 2) {
        float a0 = vok ? xp[(u + 0) * HW] : 0.f;
        float a1 = vok ? xp[(u + 1) * HW] : 0.f;
        pk[u >> 1] = f2bf_rn(a0) | (f2bf_rn(a1) << 16);
      }
      uint4 q0 = {pk[0], pk[1], pk[2], pk[3]};
      uint4 q1 = {pk[4], pk[5], pk[6], pk[7]};
      int base = px * 8, s = px & 7;
      colsA[base + ((g * 2 + 0) ^ s)] = q0;
      colsA[base + ((g * 2 + 1) ^ s)] = q1;
    }
    __syncthreads();
    int pxr = wv * 16 + lo16;
#pragma unroll
    for (int kst = 0; kst < 2; ++kst) {
      const v8s* ap0 = (const v8s*)(woff_t + (0  + lo16) * 576 + kk * 64 + kst * 32 + hi2 * 8);
      const v8s* ap1 = (const v8s*)(woff_t + (16 + lo16) * 576 + kk * 64 + kst * 32 + hi2 * 8);
      const v8s* bp  = (const v8s*)&colsA[pxr * 8 + ((kst * 4 + hi2) ^ (pxr & 7))];
      v8s bfr = *bp;
      oacc0 = __builtin_amdgcn_mfma_f32_16x16x32_bf16(*ap0, bfr, oacc0, 0, 0, 0);
      oacc1 = __builtin_amdgcn_mfma_f32_16x16x32_bf16(*ap1, bfr, oacc1, 0, 0, 0);
    }
  }
  {
    int pxw = wv * 16 + lo16;
#pragma unroll
    for (int j = 0; j < 4; ++j) {
      int oc = hi2 * 4 + j;
      pypx[oc][pxw] = oacc0[j] + b_off[oc];
    }
    if (hi2 == 0) {
#pragma unroll
      for (int j = 0; j < 2; ++j)
        pypx[16 + j][pxw] = oacc1[j] + b_off[16 + j];
    }
  }
  __syncthreads();

  v4f acc[2][2];
#pragma unroll
  for (int a = 0; a < 2; ++a)
#pragma unroll
    for (int c = 0; c < 2; ++c) acc[a][c] = (v4f){0.f, 0.f, 0.f, 0.f};

  const int co0 = (wv & 1) << 5;
  const int px0 = (wv >> 1) << 5;

  for (int kk = 0; kk < 9; ++kk) {
    if (kk) __syncthreads();
    {
      float dy = pypx[2 * kk][px], dx = pypx[2 * kk + 1][px];
      float py  = (float)(ho - 1 + kk / 3) + dy;
      float pxf = (float)(wo0 + px - 1 + kk % 3) + dx;
      float y0f = floorf(py), x0f = floorf(pxf);
      float wy1 = py - y0f,  wy0 = 1.f - wy1;
      float wx1 = pxf - x0f, wx0 = 1.f - wx1;
      bool vy0 = (y0f >= 0.f)  && (y0f < (float)Hd);
      bool vy1 = (y0f >= -1.f) && (y0f < (float)(Hd - 1));
      bool vx0 = (x0f >= 0.f)  && (x0f < (float)Wd);
      bool vx1 = (x0f >= -1.f) && (x0f < (float)(Wd - 1));
      float w00 = wy0 * wx0 * ((vy0 && vx0) ? 1.f : 0.f);
      float w01 = wy0 * wx1 * ((vy0 && vx1) ? 1.f : 0.f);
      float w10 = wy1 * wx0 * ((vy1 && vx0) ? 1.f : 0.f);
      float w11 = wy1 * wx1 * ((vy1 && vx1) ? 1.f : 0.f);
      int y0  = (int)fminf(fmaxf(y0f,       0.f), (float)(Hd - 1));
      int y1  = (int)fminf(fmaxf(y0f + 1.f, 0.f), (float)(Hd - 1));
      int x0i = (int)fminf(fmaxf(x0f,       0.f), (float)(Wd - 1));
      int x1i = (int)fminf(fmaxf(x0f + 1.f, 0.f), (float)(Wd - 1));
      const float* xp  = xb + (size_t)(g * 16) * HW;
      const float* p00 = xp + y0 * Wd + x0i;
      const float* p01 = xp + y0 * Wd + x1i;
      const float* p10 = xp + y1 * Wd + x0i;
      const float* p11 = xp + y1 * Wd + x1i;
      uint ph[8], pl[8];
#pragma unroll
      for (int u = 0; u < 16; u += 2) {
        float v0 = w00 * p00[u * HW] + w01 * p01[u * HW] +
                   w10 * p10[u * HW] + w11 * p11[u * HW];
        float v1 = w00 * p00[(u + 1) * HW] + w01 * p01[(u + 1) * HW] +
                   w10 * p10[(u + 1) * HW] + w11 * p11[(u + 1) * HW];
        uint h0, l0, h1, l1;
        split_bf(v0, h0, l0);
        split_bf(v1, h1, l1);
        ph[u >> 1] = h0 | (h1 << 16);
        pl[u >> 1] = l0 | (l1 << 16);
      }
      uint4 qh0 = {ph[0], ph[1], ph[2], ph[3]};
      uint4 qh1 = {ph[4], ph[5], ph[6], ph[7]};
      uint4 ql0 = {pl[0], pl[1], pl[2], pl[3]};
      uint4 ql1 = {pl[4], pl[5], pl[6], pl[7]};
      int base = px * 8, s = px & 7;
      colsA[base + ((g * 2 + 0) ^ s)] = qh0;
      colsA[base + ((g * 2 + 1) ^ s)] = qh1;
      colsB[base + ((g * 2 + 0) ^ s)] = ql0;
      colsB[base + ((g * 2 + 1) ^ s)] = ql1;
    }
    __syncthreads();

#pragma unroll
    for (int kst = 0; kst < 2; ++kst) {
      const int ko = kk * 64 + kst * 32 + hi2 * 8;
      v8s ah0 = *(const v8s*)(whi + (co0 +      lo16) * 576 + ko);
      v8s ah1 = *(const v8s*)(whi + (co0 + 16 + lo16) * 576 + ko);
      v8s al0 = *(const v8s*)(wlo + (co0 +      lo16) * 576 + ko);
      v8s al1 = *(const v8s*)(wlo + (co0 + 16 + lo16) * 576 + ko);
      int pr0 = px0 + lo16, pr1 = px0 + 16 + lo16;
      int k4 = kst * 4 + hi2;
      v8s bh0 = *(const v8s*)&colsA[pr0 * 8 + (k4 ^ (pr0 & 7))];
      v8s bh1 = *(const v8s*)&colsA[pr1 * 8 + (k4 ^ (pr1 & 7))];
      v8s bl0 = *(const v8s*)&colsB[pr0 * 8 + (k4 ^ (pr0 & 7))];
      v8s bl1 = *(const v8s*)&colsB[pr1 * 8 + (k4 ^ (pr1 & 7))];

      acc[0][0] = __builtin_amdgcn_mfma_f32_16x16x32_bf16(ah0, bh0, acc[0][0], 0, 0, 0);
      acc[0][0] = __builtin_amdgcn_mfma_f32_16x16x32_bf16(ah0, bl0, acc[0][0], 0, 0, 0);
      acc[0][0] = __builtin_amdgcn_mfma_f32_16x16x32_bf16(al0, bh0, acc[0][0], 0, 0, 0);
      acc[0][1] = __builtin_amdgcn_mfma_f32_16x16x32_bf16(ah0, bh1, acc[0][1], 0, 0, 0);
      acc[0][1] = __builtin_amdgcn_mfma_f32_16x16x32_bf16(ah0, bl1, acc[0][1], 0, 0, 0);
      acc[0][1] = __builtin_amdgcn_mfma_f32_16x16x32_bf16(al0, bh1, acc[0][1], 0, 0, 0);
      acc[1][0] = __builtin_amdgcn_mfma_f32_16x16x32_bf16(ah1, bh0, acc[1][0], 0, 0, 0);
      acc[1][0] = __builtin_amdgcn_mfma_f32_16x16x32_bf16(ah1, bl0, acc[1][0], 0, 0, 0);
      acc[1][0] = __builtin_amdgcn_mfma_f32_16x16x32_bf16(al1, bh0, acc[1][0], 0, 0, 0);
      acc[1][1] = __builtin_amdgcn_mfma_f32_16x16x32_bf16(ah1, bh1, acc[1][1], 0, 0, 0);
      acc[1][1] = __builtin_amdgcn_mfma_f32_16x16x32_bf16(ah1, bl1, acc[1][1], 0, 0, 0);
      acc[1][1] = __builtin_amdgcn_mfma_f32_16x16x32_bf16(al1, bh1, acc[1][1], 0, 0, 0);
    }
  }

  const int wo_b = wo0 + px0 + lo16;
#pragma unroll
  for (int ct = 0; ct < 2; ++ct) {
#pragma unroll
    for (int pt = 0; pt < 2; ++pt) {
#pragma unroll
      for (int j = 0; j < 4; ++j) {
        int co = co0 + ct * 16 + hi2 * 4 + j;
        out[(((size_t)b * COUT + co) * Hd + ho) * Wd + wo_b + pt * 16] = acc[ct][pt][j];
      }
    }
  }
}

extern "C" void kernel_launch(void* const* d_in, const int* in_sizes, int n_in,
                              void* d_out, int out_size, void* d_ws, size_t ws_size,
                              hipStream_t stream) {
  const float* x     = (const float*)d_in[0];
  const float* w_off = (const float*)d_in[1];
  const float* b_off = (const float*)d_in[2];
  const float* w     = (const float*)d_in[3];
  float* out = (float*)d_out;

  const size_t XT_ELT = (size_t)8 * HW * CIN;          // 8,388,608 ushorts
  const size_t NEED   = XT_ELT * 2 + 2u * (18432 + 36864 + 36864);

  ushort* base = (ushort*)d_ws;
  ushort *x_t, *woff_t, *whi, *wlo;
  bool fast = (ws_size >= NEED);
  if (fast) {
    x_t    = base;
    woff_t = base + XT_ELT;
  } else {
    x_t    = nullptr;
    woff_t = base;
  }
  whi = woff_t + 18432;
  wlo = whi + 36864;

  repack<<<144, 256, 0, stream>>>(w_off, w, woff_t, whi, wlo);

  if (fast) {
    transpose_nhwc<<<8 * Hd, 256, 0, stream>>>(x, x_t);
    dconv_nhwc2<<<2048, 256, 0, stream>>>(x_t, b_off, woff_t, whi, wlo, out);
  } else {
    dconv_old<<<2048, 256, 0, stream>>>(x, b_off, woff_t, whi, wlo, out);
  }
}

// Round 6
// 190.035 us; speedup vs baseline: 5.3814x; 1.0088x over previous
//
#include <hip/hip_runtime.h>

typedef float  v4f __attribute__((ext_vector_type(4)));
typedef short  v8s __attribute__((ext_vector_type(8)));
typedef uint   v4u __attribute__((ext_vector_type(4)));

#define Hd   128
#define Wd   128
#define HW   (Hd*Wd)
#define CIN  64
#define COUT 64

__device__ __forceinline__ uint f2bf_rn(float v) {
  uint u = __builtin_bit_cast(uint, v);
  u += 0x7FFFu + ((u >> 16) & 1u);
  return u >> 16;
}

__device__ __forceinline__ void split_bf(float v, uint& h, uint& l) {
  uint u = __builtin_bit_cast(uint, v);
  uint r = u + 0x7FFFu + ((u >> 16) & 1u);
  h = r >> 16;
  float hf = __builtin_bit_cast(float, (r >> 16) << 16);
  float lf = v - hf;
  l = __builtin_bit_cast(uint, lf) >> 16;
}

// ---- repack weights ----
__global__ __launch_bounds__(256) void repack(
    const float* __restrict__ w_off, const float* __restrict__ w,
    ushort* __restrict__ woff_t, ushort* __restrict__ whi,
    ushort* __restrict__ wlo) {
  int i = blockIdx.x * 256 + threadIdx.x;        // 0..36863 (=64*576)
  int co = i / 576, k = i - co * 576;
  int kk = k >> 6, ci = k & 63;
  float wv = w[(co * 64 + ci) * 9 + kk];
  uint h, l;
  split_bf(wv, h, l);
  whi[i] = (ushort)h;
  wlo[i] = (ushort)l;
  if (i < 32 * 576) {
    float v = (co < 18) ? w_off[(co * 64 + ci) * 9 + kk] : 0.f;
    woff_t[i] = (ushort)f2bf_rn(v);
  }
}

// ---- NCHW fp32 -> NHWC bf16 transpose ----
__global__ __launch_bounds__(256) void transpose_nhwc(
    const float* __restrict__ x, ushort* __restrict__ x_t) {
  __shared__ ushort tile[128][72];
  const int t  = threadIdx.x;
  const int by = blockIdx.x;                     // b*128 + y
  const float* xp = x + (size_t)(by >> 7) * (CIN * HW) + (size_t)(by & 127) * Wd;
#pragma unroll
  for (int r = 0; r < 32; ++r) {
    int idx = r * 256 + t;
    int ci = idx >> 7, xw = idx & 127;
    tile[xw][ci] = (ushort)f2bf_rn(xp[(size_t)ci * HW + xw]);
  }
  __syncthreads();
  ushort* op = x_t + (size_t)by * (Wd * CIN);
#pragma unroll
  for (int r = 0; r < 4; ++r) {
    int c = r * 256 + t;
    int xw = c >> 3, q = c & 7;
    v4u v = *(const v4u*)&tile[xw][q * 8];
    *(v4u*)(op + xw * 64 + q * 8) = v;
  }
}

// ========== round-5 structure + dbuf pipeline + single-bf16 B ==========
__global__ __launch_bounds__(256, 4) void dconv3(
    const ushort* __restrict__ x_t, const float* __restrict__ b_off,
    const ushort* __restrict__ woff_t, const ushort* __restrict__ whi,
    const ushort* __restrict__ wlo, float* __restrict__ out) {

  __shared__ v4u  cols0[64 * 8];
  __shared__ v4u  cols1[64 * 8];
  __shared__ float pypx[18][64];

  const int t    = threadIdx.x;
  const int lane = t & 63;
  const int wv   = t >> 6;
  const int lo16 = lane & 15, hi2 = lane >> 4;
  const int wid = ((blockIdx.x & 7) << 8) | (blockIdx.x >> 3);
  const int b   = wid >> 8;
  const int ho  = (wid >> 1) & 127;
  const int wo0 = (wid & 1) << 6;
  const int px = t & 63;
  const int g  = t >> 6;
  const ushort* xtb = x_t + (size_t)b * (HW * CIN);

  const int wbase = px * 8;
  const int swz_w = px & 7;

  // ---------------- phase A: offset conv, double-buffered ----------------
  v4f oacc0 = {0.f, 0.f, 0.f, 0.f};
  v4f oacc1 = {0.f, 0.f, 0.f, 0.f};

#define LOADA(KN, Q0, Q1) do {                                               \
    int yy = ho - 1 + (KN) / 3;                                              \
    int xx = wo0 + px - 1 + (KN) % 3;                                        \
    bool vok = (yy >= 0) && (yy < Hd) && (xx >= 0) && (xx < Wd);             \
    (Q0) = (v4u){0u, 0u, 0u, 0u};                                            \
    (Q1) = (v4u){0u, 0u, 0u, 0u};                                            \
    if (vok) {                                                               \
      const ushort* p = xtb + ((yy << 7) + xx) * 64 + g * 16;                \
      (Q0) = *(const v4u*)p;                                                 \
      (Q1) = *(const v4u*)(p + 8);                                           \
    }                                                                        \
  } while (0)

#define WRITECOLS(BUF, Q0, Q1) do {                                          \
    (BUF)[wbase + ((g * 2 + 0) ^ swz_w)] = (Q0);                             \
    (BUF)[wbase + ((g * 2 + 1) ^ swz_w)] = (Q1);                             \
  } while (0)

  {
    v4u q0, q1;
    LOADA(0, q0, q1);
    WRITECOLS(cols0, q0, q1);
  }
  __syncthreads();

  const int pxr = wv * 16 + lo16;
#pragma unroll
  for (int kk = 0; kk < 9; ++kk) {
    v4u n0, n1;
    if (kk < 8) LOADA(kk + 1, n0, n1);
    const v4u* buf = (kk & 1) ? cols1 : cols0;
#pragma unroll
    for (int kst = 0; kst < 2; ++kst) {
      v8s a0  = *(const v8s*)(woff_t + (0  + lo16) * 576 + kk * 64 + kst * 32 + hi2 * 8);
      v8s a1  = *(const v8s*)(woff_t + (16 + lo16) * 576 + kk * 64 + kst * 32 + hi2 * 8);
      v8s bfr = *(const v8s*)&buf[pxr * 8 + ((kst * 4 + hi2) ^ (pxr & 7))];
      oacc0 = __builtin_amdgcn_mfma_f32_16x16x32_bf16(a0, bfr, oacc0, 0, 0, 0);
      oacc1 = __builtin_amdgcn_mfma_f32_16x16x32_bf16(a1, bfr, oacc1, 0, 0, 0);
    }
    if (kk < 8) {
      v4u* bw = (kk & 1) ? cols0 : cols1;    // buffer (kk+1)&1
      WRITECOLS(bw, n0, n1);
      __syncthreads();
    }
  }
#undef LOADA

  {
#pragma unroll
    for (int j = 0; j < 4; ++j) {
      int oc = hi2 * 4 + j;
      pypx[oc][pxr] = oacc0[j] + b_off[oc];
    }
    if (hi2 == 0) {
#pragma unroll
      for (int j = 0; j < 2; ++j)
        pypx[16 + j][pxr] = oacc1[j] + b_off[16 + j];
    }
  }
  __syncthreads();

  // ---------------- phase B: dbuf blend (hi-only B) + split-A GEMM --------
  v4f acc00 = {0.f, 0.f, 0.f, 0.f};
  v4f acc01 = {0.f, 0.f, 0.f, 0.f};
  v4f acc10 = {0.f, 0.f, 0.f, 0.f};
  v4f acc11 = {0.f, 0.f, 0.f, 0.f};

  const int co0 = (wv & 1) << 5;
  const int px0 = (wv >> 1) << 5;
  const int pr0 = px0 + lo16, pr1 = px0 + 16 + lo16;

  v4u g00a, g00b, g01a, g01b, g10a, g10b, g11a, g11b;
  float w00, w01, w10, w11;

#define PF(KN) do {                                                          \
    float dy  = pypx[2 * (KN)][px], dxo = pypx[2 * (KN) + 1][px];            \
    float py  = (float)(ho - 1 + (KN) / 3) + dy;                             \
    float pxf = (float)(wo0 + px - 1 + (KN) % 3) + dxo;                      \
    float y0f = floorf(py), x0f = floorf(pxf);                               \
    float wy1 = py - y0f, wy0 = 1.f - wy1;                                   \
    float wx1 = pxf - x0f, wx0 = 1.f - wx1;                                  \
    bool vy0 = (y0f >= 0.f)  && (y0f < 128.f);                               \
    bool vy1 = (y0f >= -1.f) && (y0f < 127.f);                               \
    bool vx0 = (x0f >= 0.f)  && (x0f < 128.f);                               \
    bool vx1 = (x0f >= -1.f) && (x0f < 127.f);                               \
    w00 = wy0 * wx0 * ((vy0 && vx0) ? 1.f : 0.f);                            \
    w01 = wy0 * wx1 * ((vy0 && vx1) ? 1.f : 0.f);                            \
    w10 = wy1 * wx0 * ((vy1 && vx0) ? 1.f : 0.f);                            \
    w11 = wy1 * wx1 * ((vy1 && vx1) ? 1.f : 0.f);                            \
    int y0  = (int)fminf(fmaxf(y0f,       0.f), 127.f);                      \
    int y1  = (int)fminf(fmaxf(y0f + 1.f, 0.f), 127.f);                      \
    int x0i = (int)fminf(fmaxf(x0f,       0.f), 127.f);                      \
    int x1i = (int)fminf(fmaxf(x0f + 1.f, 0.f), 127.f);                      \
    int o00 = ((y0 << 7) + x0i) * 64 + g * 16;                               \
    int o01 = ((y0 << 7) + x1i) * 64 + g * 16;                               \
    int o10 = ((y1 << 7) + x0i) * 64 + g * 16;                               \
    int o11 = ((y1 << 7) + x1i) * 64 + g * 16;                               \
    g00a = *(const v4u*)(xtb + o00); g00b = *(const v4u*)(xtb + o00 + 8);    \
    g01a = *(const v4u*)(xtb + o01); g01b = *(const v4u*)(xtb + o01 + 8);    \
    g10a = *(const v4u*)(xtb + o10); g10b = *(const v4u*)(xtb + o10 + 8);    \
    g11a = *(const v4u*)(xtb + o11); g11b = *(const v4u*)(xtb + o11 + 8);    \
  } while (0)

#define BWH(DST) do {                                                        \
    uint ph[8];                                                              \
    _Pragma("unroll")                                                        \
    for (int j = 0; j < 8; ++j) {                                            \
      uint u00 = (j < 4) ? g00a[j] : g00b[j - 4];                            \
      uint u01 = (j < 4) ? g01a[j] : g01b[j - 4];                            \
      uint u10 = (j < 4) ? g10a[j] : g10b[j - 4];                            \
      uint u11 = (j < 4) ? g11a[j] : g11b[j - 4];                            \
      float a0 = __builtin_bit_cast(float, u00 << 16);                       \
      float a1 = __builtin_bit_cast(float, u01 << 16);                       \
      float a2 = __builtin_bit_cast(float, u10 << 16);                       \
      float a3 = __builtin_bit_cast(float, u11 << 16);                       \
      float v0 = w00 * a0; v0 = fmaf(w01, a1, v0);                           \
      v0 = fmaf(w10, a2, v0); v0 = fmaf(w11, a3, v0);                        \
      float h0 = __builtin_bit_cast(float, u00 & 0xFFFF0000u);               \
      float h1 = __builtin_bit_cast(float, u01 & 0xFFFF0000u);               \
      float h2 = __builtin_bit_cast(float, u10 & 0xFFFF0000u);               \
      float h3 = __builtin_bit_cast(float, u11 & 0xFFFF0000u);               \
      float v1 = w00 * h0; v1 = fmaf(w01, h1, v1);                           \
      v1 = fmaf(w10, h2, v1); v1 = fmaf(w11, h3, v1);                        \
      ph[j] = f2bf_rn(v0) | (f2bf_rn(v1) << 16);                             \
    }                                                                        \
    v4u qh0 = {ph[0], ph[1], ph[2], ph[3]};                                  \
    v4u qh1 = {ph[4], ph[5], ph[6], ph[7]};                                  \
    (DST)[wbase + ((g * 2 + 0) ^ swz_w)] = qh0;                              \
    (DST)[wbase + ((g * 2 + 1) ^ swz_w)] = qh1;                              \
  } while (0)

  PF(0);
  BWH(cols0);
  __syncthreads();

#pragma unroll
  for (int kk = 0; kk < 9; ++kk) {
    if (kk < 8) PF(kk + 1);

    const v4u* buf = (kk & 1) ? cols1 : cols0;
#pragma unroll
    for (int kst = 0; kst < 2; ++kst) {
      const int ko = kk * 64 + kst * 32 + hi2 * 8;
      const int k4 = kst * 4 + hi2;
      v8s bh0 = *(const v8s*)&buf[pr0 * 8 + (k4 ^ (pr0 & 7))];
      v8s bh1 = *(const v8s*)&buf[pr1 * 8 + (k4 ^ (pr1 & 7))];
      v8s ah0 = *(const v8s*)(whi + (co0 +      lo16) * 576 + ko);
      v8s al0 = *(const v8s*)(wlo + (co0 +      lo16) * 576 + ko);
      v8s ah1 = *(const v8s*)(whi + (co0 + 16 + lo16) * 576 + ko);
      v8s al1 = *(const v8s*)(wlo + (co0 + 16 + lo16) * 576 + ko);
      acc00 = __builtin_amdgcn_mfma_f32_16x16x32_bf16(ah0, bh0, acc00, 0, 0, 0);
      acc00 = __builtin_amdgcn_mfma_f32_16x16x32_bf16(al0, bh0, acc00, 0, 0, 0);
      acc01 = __builtin_amdgcn_mfma_f32_16x16x32_bf16(ah0, bh1, acc01, 0, 0, 0);
      acc01 = __builtin_amdgcn_mfma_f32_16x16x32_bf16(al0, bh1, acc01, 0, 0, 0);
      acc10 = __builtin_amdgcn_mfma_f32_16x16x32_bf16(ah1, bh0, acc10, 0, 0, 0);
      acc10 = __builtin_amdgcn_mfma_f32_16x16x32_bf16(al1, bh0, acc10, 0, 0, 0);
      acc11 = __builtin_amdgcn_mfma_f32_16x16x32_bf16(ah1, bh1, acc11, 0, 0, 0);
      acc11 = __builtin_amdgcn_mfma_f32_16x16x32_bf16(al1, bh1, acc11, 0, 0, 0);
    }

    if (kk < 8) {
      v4u* bw = (kk & 1) ? cols0 : cols1;
      BWH(bw);
      __syncthreads();
    }
  }
#undef PF
#undef BWH
#undef WRITECOLS

  // ---------------- epilogue ----------------
  const int wo_b = wo0 + px0 + lo16;
#pragma unroll
  for (int j = 0; j < 4; ++j) {
    int coA = co0 + hi2 * 4 + j;
    int coB = co0 + 16 + hi2 * 4 + j;
    out[(((size_t)b * COUT + coA) * Hd + ho) * Wd + wo_b]      = acc00[j];
    out[(((size_t)b * COUT + coA) * Hd + ho) * Wd + wo_b + 16] = acc01[j];
    out[(((size_t)b * COUT + coB) * Hd + ho) * Wd + wo_b]      = acc10[j];
    out[(((size_t)b * COUT + coB) * Hd + ho) * Wd + wo_b + 16] = acc11[j];
  }
}

// =================== fallback (round-3 kernel, NCHW fp32 gathers) ==========
__global__ __launch_bounds__(256, 4) void dconv_old(
    const float* __restrict__ x, const float* __restrict__ b_off,
    const ushort* __restrict__ woff_t, const ushort* __restrict__ whi,
    const ushort* __restrict__ wlo, float* __restrict__ out) {

  __shared__ uint4 colsA[64 * 8];
  __shared__ uint4 colsB[64 * 8];
  __shared__ float pypx[18][64];

  const int t    = threadIdx.x;
  const int lane = t & 63;
  const int wv   = t >> 6;
  const int lo16 = lane & 15, hi2 = lane >> 4;
  const int wid = ((blockIdx.x & 7) << 8) | (blockIdx.x >> 3);
  const int b   = wid >> 8;
  const int ho  = (wid >> 1) & 127;
  const int wo0 = (wid & 1) << 6;
  const int px = t & 63;
  const int g  = t >> 6;
  const float* xb = x + (size_t)b * (CIN * HW);

  v4f oacc0 = {0.f, 0.f, 0.f, 0.f};
  v4f oacc1 = {0.f, 0.f, 0.f, 0.f};

  for (int kk = 0; kk < 9; ++kk) {
    if (kk) __syncthreads();
    {
      int yy = ho - 1 + kk / 3;
      int xx = wo0 + px - 1 + kk % 3;
      bool vok = (yy >= 0) && (yy < Hd) && (xx >= 0) && (xx < Wd);
      const float* xp = xb + (size_t)(g * 16) * HW + yy * Wd + xx;
      uint pk[8];
#pragma unroll
      for (int u = 0; u < 16; u += 2) {
        float a0 = vok ? xp[(u + 0) * HW] : 0.f;
        float a1 = vok ? xp[(u + 1) * HW] : 0.f;
        pk[u >> 1] = f2bf_rn(a0) | (f2bf_rn(a1) << 16);
      }
      uint4 q0 = {pk[0], pk[1], pk[2], pk[3]};
      uint4 q1 = {pk[4], pk[5], pk[6], pk[7]};
      int base = px * 8, s = px & 7;
      colsA[base + ((g * 2 + 0) ^ s)] = q0;
      colsA[base + ((g * 2 + 1) ^ s)] = q1;
    }
    __syncthreads();
    int pxr = wv * 16 + lo16;
#pragma unroll
    for (int kst = 0; kst < 2; ++kst) {
      const v8s* ap0 = (const v8s*)(woff_t + (0  + lo16) * 576 + kk * 64 + kst * 32 + hi2 * 8);
      const v8s* ap1 = (const v8s*)(woff_t + (16 + lo16) * 576 + kk * 64 + kst * 32 + hi2 * 8);
      const v8s* bp  = (const v8s*)&colsA[pxr * 8 + ((kst * 4 + hi2) ^ (pxr & 7))];
      v8s bfr = *bp;
      oacc0 = __builtin_amdgcn_mfma_f32_16x16x32_bf16(*ap0, bfr, oacc0, 0, 0, 0);
      oacc1 = __builtin_amdgcn_mfma_f32_16x16x32_bf16(*ap1, bfr, oacc1, 0, 0, 0);
    }
  }
  {
    int pxw = wv * 16 + lo16;
#pragma unroll
    for (int j = 0; j < 4; ++j) {
      int oc = hi2 * 4 + j;
      pypx[oc][pxw] = oacc0[j] + b_off[oc];
    }
    if (hi2 == 0) {
#pragma unroll
      for (int j = 0; j < 2; ++j)
        pypx[16 + j][pxw] = oacc1[j] + b_off[16 + j];
    }
  }
  __syncthreads();

  v4f acc[2][2];
#pragma unroll
  for (int a = 0; a < 2; ++a)
#pragma unroll
    for (int c = 0; c < 2; ++c) acc[a][c] = (v4f){0.f, 0.f, 0.f, 0.f};

  const int co0 = (wv & 1) << 5;
  const int px0 = (wv >> 1) << 5;

  for (int kk = 0; kk < 9; ++kk) {
    if (kk) __syncthreads();
    {
      float dy = pypx[2 * kk][px], dx = pypx[2 * kk + 1][px];
      float py  = (float)(ho - 1 + kk / 3) + dy;
      float pxf = (float)(wo0 + px - 1 + kk % 3) + dx;
      float y0f = floorf(py), x0f = floorf(pxf);
      float wy1 = py - y0f,  wy0 = 1.f - wy1;
      float wx1 = pxf - x0f, wx0 = 1.f - wx1;
      bool vy0 = (y0f >= 0.f)  && (y0f < (float)Hd);
      bool vy1 = (y0f >= -1.f) && (y0f < (float)(Hd - 1));
      bool vx0 = (x0f >= 0.f)  && (x0f < (float)Wd);
      bool vx1 = (x0f >= -1.f) && (x0f < (float)(Wd - 1));
      float w00 = wy0 * wx0 * ((vy0 && vx0) ? 1.f : 0.f);
      float w01 = wy0 * wx1 * ((vy0 && vx1) ? 1.f : 0.f);
      float w10 = wy1 * wx0 * ((vy1 && vx0) ? 1.f : 0.f);
      float w11 = wy1 * wx1 * ((vy1 && vx1) ? 1.f : 0.f);
      int y0  = (int)fminf(fmaxf(y0f,       0.f), (float)(Hd - 1));
      int y1  = (int)fminf(fmaxf(y0f + 1.f, 0.f), (float)(Hd - 1));
      int x0i = (int)fminf(fmaxf(x0f,       0.f), (float)(Wd - 1));
      int x1i = (int)fminf(fmaxf(x0f + 1.f, 0.f), (float)(Wd - 1));
      const float* xp  = xb + (size_t)(g * 16) * HW;
      const float* p00 = xp + y0 * Wd + x0i;
      const float* p01 = xp + y0 * Wd + x1i;
      const float* p10 = xp + y1 * Wd + x0i;
      const float* p11 = xp + y1 * Wd + x1i;
      uint ph[8], pl[8];
#pragma unroll
      for (int u = 0; u < 16; u += 2) {
        float v0 = w00 * p00[u * HW] + w01 * p01[u * HW] +
                   w10 * p10[u * HW] + w11 * p11[u * HW];
        float v1 = w00 * p00[(u + 1) * HW] + w01 * p01[(u + 1) * HW] +
                   w10 * p10[(u + 1) * HW] + w11 * p11[(u + 1) * HW];
        uint h0, l0, h1, l1;
        split_bf(v0, h0, l0);
        split_bf(v1, h1, l1);
        ph[u >> 1] = h0 | (h1 << 16);
        pl[u >> 1] = l0 | (l1 << 16);
      }
      uint4 qh0 = {ph[0], ph[1], ph[2], ph[3]};
      uint4 qh1 = {ph[4], ph[5], ph[6], ph[7]};
      uint4 ql0 = {pl[0], pl[1], pl[2], pl[3]};
      uint4 ql1 = {pl[4], pl[5], pl[6], pl[7]};
      int base = px * 8, s = px & 7;
      colsA[base + ((g * 2 + 0) ^ s)] = qh0;
      colsA[base + ((g * 2 + 1) ^ s)] = qh1;
      colsB[base + ((g * 2 + 0) ^ s)] = ql0;
      colsB[base + ((g * 2 + 1) ^ s)] = ql1;
    }
    __syncthreads();

#pragma unroll
    for (int kst = 0; kst < 2; ++kst) {
      const int ko = kk * 64 + kst * 32 + hi2 * 8;
      v8s ah0 = *(const v8s*)(whi + (co0 +      lo16) * 576 + ko);
      v8s ah1 = *(const v8s*)(whi + (co0 + 16 + lo16) * 576 + ko);
      v8s al0 = *(const v8s*)(wlo + (co0 +      lo16) * 576 + ko);
      v8s al1 = *(const v8s*)(wlo + (co0 + 16 + lo16) * 576 + ko);
      int pr0 = px0 + lo16, pr1 = px0 + 16 + lo16;
      int k4 = kst * 4 + hi2;
      v8s bh0 = *(const v8s*)&colsA[pr0 * 8 + (k4 ^ (pr0 & 7))];
      v8s bh1 = *(const v8s*)&colsA[pr1 * 8 + (k4 ^ (pr1 & 7))];
      v8s bl0 = *(const v8s*)&colsB[pr0 * 8 + (k4 ^ (pr0 & 7))];
      v8s bl1 = *(const v8s*)&colsB[pr1 * 8 + (k4 ^ (pr1 & 7))];

      acc[0][0] = __builtin_amdgcn_mfma_f32_16x16x32_bf16(ah0, bh0, acc[0][0], 0, 0, 0);
      acc[0][0] = __builtin_amdgcn_mfma_f32_16x16x32_bf16(ah0, bl0, acc[0][0], 0, 0, 0);
      acc[0][0] = __builtin_amdgcn_mfma_f32_16x16x32_bf16(al0, bh0, acc[0][0], 0, 0, 0);
      acc[0][1] = __builtin_amdgcn_mfma_f32_16x16x32_bf16(ah0, bh1, acc[0][1], 0, 0, 0);
      acc[0][1] = __builtin_amdgcn_mfma_f32_16x16x32_bf16(ah0, bl1, acc[0][1], 0, 0, 0);
      acc[0][1] = __builtin_amdgcn_mfma_f32_16x16x32_bf16(al0, bh1, acc[0][1], 0, 0, 0);
      acc[1][0] = __builtin_amdgcn_mfma_f32_16x16x32_bf16(ah1, bh0, acc[1][0], 0, 0, 0);
      acc[1][0] = __builtin_amdgcn_mfma_f32_16x16x32_bf16(ah1, bl0, acc[1][0], 0, 0, 0);
      acc[1][0] = __builtin_amdgcn_mfma_f32_16x16x32_bf16(al1, bh0, acc[1][0], 0, 0, 0);
      acc[1][1] = __builtin_amdgcn_mfma_f32_16x16x32_bf16(ah1, bh1, acc[1][1], 0, 0, 0);
      acc[1][1] = __builtin_amdgcn_mfma_f32_16x16x32_bf16(ah1, bl1, acc[1][1], 0, 0, 0);
      acc[1][1] = __builtin_amdgcn_mfma_f32_16x16x32_bf16(al1, bh1, acc[1][1], 0, 0, 0);
    }
  }

  const int wo_b = wo0 + px0 + lo16;
#pragma unroll
  for (int ct = 0; ct < 2; ++ct) {
#pragma unroll
    for (int pt = 0; pt < 2; ++pt) {
#pragma unroll
      for (int j = 0; j < 4; ++j) {
        int co = co0 + ct * 16 + hi2 * 4 + j;
        out[(((size_t)b * COUT + co) * Hd + ho) * Wd + wo_b + pt * 16] = acc[ct][pt][j];
      }
    }
  }
}

extern "C" void kernel_launch(void* const* d_in, const int* in_sizes, int n_in,
                              void* d_out, int out_size, void* d_ws, size_t ws_size,
                              hipStream_t stream) {
  const float* x     = (const float*)d_in[0];
  const float* w_off = (const float*)d_in[1];
  const float* b_off = (const float*)d_in[2];
  const float* w     = (const float*)d_in[3];
  float* out = (float*)d_out;

  const size_t XT_ELT = (size_t)8 * HW * CIN;          // 8,388,608 ushorts
  const size_t NEED   = XT_ELT * 2 + 2u * (18432 + 36864 + 36864);

  ushort* base = (ushort*)d_ws;
  ushort *x_t, *woff_t, *whi, *wlo;
  bool fast = (ws_size >= NEED);
  if (fast) {
    x_t    = base;
    woff_t = base + XT_ELT;
  } else {
    x_t    = nullptr;
    woff_t = base;
  }
  whi = woff_t + 18432;
  wlo = whi + 36864;

  repack<<<144, 256, 0, stream>>>(w_off, w, woff_t, whi, wlo);

  if (fast) {
    transpose_nhwc<<<8 * Hd, 256, 0, stream>>>(x, x_t);
    dconv3<<<2048, 256, 0, stream>>>(x_t, b_off, woff_t, whi, wlo, out);
  } else {
    dconv_old<<<2048, 256, 0, stream>>>(x, b_off, woff_t, whi, wlo, out);
  }
}

// Round 7
// 155.909 us; speedup vs baseline: 6.5593x; 1.2189x over previous
//
#include <hip/hip_runtime.h>

typedef float  v4f __attribute__((ext_vector_type(4)));
typedef short  v8s __attribute__((ext_vector_type(8)));
typedef uint   v4u __attribute__((ext_vector_type(4)));

#define Hd   128
#define Wd   128
#define HW   (Hd*Wd)
#define CIN  64
#define COUT 64
#define SROWS 5
#define SCOLS 72
#define SCH   (SROWS*SCOLS*8)   // 2880 16B-chunks = 46080 B

__device__ __forceinline__ uint f2bf_rn(float v) {
  uint u = __builtin_bit_cast(uint, v);
  u += 0x7FFFu + ((u >> 16) & 1u);
  return u >> 16;
}

__device__ __forceinline__ void split_bf(float v, uint& h, uint& l) {
  uint u = __builtin_bit_cast(uint, v);
  uint r = u + 0x7FFFu + ((u >> 16) & 1u);
  h = r >> 16;
  float hf = __builtin_bit_cast(float, (r >> 16) << 16);
  float lf = v - hf;
  l = __builtin_bit_cast(uint, lf) >> 16;
}

// ---- repack weights ----
__global__ __launch_bounds__(256) void repack(
    const float* __restrict__ w_off, const float* __restrict__ w,
    ushort* __restrict__ woff_t, ushort* __restrict__ whi,
    ushort* __restrict__ wlo) {
  int i = blockIdx.x * 256 + threadIdx.x;        // 0..36863 (=64*576)
  int co = i / 576, k = i - co * 576;
  int kk = k >> 6, ci = k & 63;
  float wv = w[(co * 64 + ci) * 9 + kk];
  uint h, l;
  split_bf(wv, h, l);
  whi[i] = (ushort)h;
  wlo[i] = (ushort)l;
  if (i < 32 * 576) {
    float v = (co < 18) ? w_off[(co * 64 + ci) * 9 + kk] : 0.f;
    woff_t[i] = (ushort)f2bf_rn(v);
  }
}

// ---- NCHW fp32 -> NHWC bf16 transpose ----
__global__ __launch_bounds__(256) void transpose_nhwc(
    const float* __restrict__ x, ushort* __restrict__ x_t) {
  __shared__ ushort tile[128][72];
  const int t  = threadIdx.x;
  const int by = blockIdx.x;                     // b*128 + y
  const float* xp = x + (size_t)(by >> 7) * (CIN * HW) + (size_t)(by & 127) * Wd;
#pragma unroll
  for (int r = 0; r < 32; ++r) {
    int idx = r * 256 + t;
    int ci = idx >> 7, xw = idx & 127;
    tile[xw][ci] = (ushort)f2bf_rn(xp[(size_t)ci * HW + xw]);
  }
  __syncthreads();
  ushort* op = x_t + (size_t)by * (Wd * CIN);
#pragma unroll
  for (int r = 0; r < 4; ++r) {
    int c = r * 256 + t;
    int xw = c >> 3, q = c & 7;
    v4u v = *(const v4u*)&tile[xw][q * 8];
    *(v4u*)(op + xw * 64 + q * 8) = v;
  }
}

// blend one MFMA B-fragment (8 ci = granule k4) for one pixel, from LDS strip
// (in-strip) or global x_t (fallback).
__device__ __forceinline__ v8s blend_frag(
    const v4u* __restrict__ strip, const ushort* __restrict__ xtb,
    int yr, int xr, int y0i, int x0i, int k4, bool instrip,
    float w00, float w01, float w10, float w11) {
  v4u t00, t01, t10, t11;
  if (instrip) {
    int cA = (yr * SCOLS + xr) * 8 + k4;
    int cB = cA + 8;
    int sA = xr & 7, sB = (xr + 1) & 7;
    t00 = strip[cA ^ sA];
    t01 = strip[cB ^ sB];
    t10 = strip[(cA + SCOLS * 8) ^ sA];
    t11 = strip[(cB + SCOLS * 8) ^ sB];
  } else {
    int y0c = min(max(y0i, 0), 127), y1c = min(max(y0i + 1, 0), 127);
    int x0c = min(max(x0i, 0), 127), x1c = min(max(x0i + 1, 0), 127);
    t00 = *(const v4u*)(xtb + ((y0c << 7) + x0c) * 64 + k4 * 8);
    t01 = *(const v4u*)(xtb + ((y0c << 7) + x1c) * 64 + k4 * 8);
    t10 = *(const v4u*)(xtb + ((y1c << 7) + x0c) * 64 + k4 * 8);
    t11 = *(const v4u*)(xtb + ((y1c << 7) + x1c) * 64 + k4 * 8);
  }
  uint ph[4];
#pragma unroll
  for (int j = 0; j < 4; ++j) {
    uint u00 = t00[j], u01 = t01[j], u10 = t10[j], u11 = t11[j];
    float a0 = __builtin_bit_cast(float, u00 << 16);
    float a1 = __builtin_bit_cast(float, u01 << 16);
    float a2 = __builtin_bit_cast(float, u10 << 16);
    float a3 = __builtin_bit_cast(float, u11 << 16);
    float v0 = w00 * a0; v0 = fmaf(w01, a1, v0);
    v0 = fmaf(w10, a2, v0); v0 = fmaf(w11, a3, v0);
    float h0 = __builtin_bit_cast(float, u00 & 0xFFFF0000u);
    float h1 = __builtin_bit_cast(float, u01 & 0xFFFF0000u);
    float h2 = __builtin_bit_cast(float, u10 & 0xFFFF0000u);
    float h3 = __builtin_bit_cast(float, u11 & 0xFFFF0000u);
    float v1 = w00 * h0; v1 = fmaf(w01, h1, v1);
    v1 = fmaf(w10, h2, v1); v1 = fmaf(w11, h3, v1);
    ph[j] = f2bf_rn(v0) | (f2bf_rn(v1) << 16);
  }
  v4u q = {ph[0], ph[1], ph[2], ph[3]};
  return __builtin_bit_cast(v8s, q);
}

// ============ strip-staged fused kernel: 2 barriers total ============
__global__ __launch_bounds__(256, 3) void dconv4(
    const ushort* __restrict__ x_t, const float* __restrict__ b_off,
    const ushort* __restrict__ woff_t, const ushort* __restrict__ whi,
    const ushort* __restrict__ wlo, float* __restrict__ out) {

  __shared__ v4u   strip[SCH];       // 46080 B
  __shared__ float pypx[18][64];     //  4608 B

  const int t    = threadIdx.x;
  const int lane = t & 63;
  const int wv   = t >> 6;
  const int lo16 = lane & 15, hi2 = lane >> 4;
  const int wid = ((blockIdx.x & 7) << 8) | (blockIdx.x >> 3);
  const int b   = wid >> 8;
  const int ho  = (wid >> 1) & 127;
  const int wo0 = (wid & 1) << 6;
  const ushort* xtb = x_t + (size_t)b * (HW * CIN);

  // ---- stage strip: rows [ho-2, ho+2] x cols [wo0-2, wo0+69], zero-filled OOB
  const int row0 = ho - 2, x0s = wo0 - 2;
#pragma unroll
  for (int it = 0; it < 12; ++it) {
    int ch = it * 256 + t;
    if (ch < SCH) {
      int k8 = ch & 7;
      int rc = ch >> 3;
      int c  = rc % SCOLS;
      int r  = rc / SCOLS;
      int y  = row0 + r, xg = x0s + c;
      v4u v = {0u, 0u, 0u, 0u};
      if (y >= 0 && y < Hd && xg >= 0 && xg < Wd)
        v = *(const v4u*)(xtb + ((y << 7) + xg) * 64 + k8 * 8);
      strip[ch ^ (c & 7)] = v;   // granule swizzle: slot k8^(c&7)
    }
  }
  __syncthreads();

  // ---- phase A: offset conv, B-frags straight from strip ----
  v4f oacc0 = {0.f, 0.f, 0.f, 0.f};
  v4f oacc1 = {0.f, 0.f, 0.f, 0.f};
  const int pxr = wv * 16 + lo16;
#pragma unroll
  for (int kk = 0; kk < 9; ++kk) {
    const int rr = kk / 3, dxk = kk % 3;
    const int cr = pxr + 1 + dxk;              // strip col of integer tap
#pragma unroll
    for (int kst = 0; kst < 2; ++kst) {
      const int k4 = kst * 4 + hi2;
      v8s bfr = *(const v8s*)&strip[(((rr + 1) * SCOLS + cr) * 8 + k4) ^ (cr & 7)];
      v8s a0  = *(const v8s*)(woff_t + (0  + lo16) * 576 + kk * 64 + kst * 32 + hi2 * 8);
      v8s a1  = *(const v8s*)(woff_t + (16 + lo16) * 576 + kk * 64 + kst * 32 + hi2 * 8);
      oacc0 = __builtin_amdgcn_mfma_f32_16x16x32_bf16(a0, bfr, oacc0, 0, 0, 0);
      oacc1 = __builtin_amdgcn_mfma_f32_16x16x32_bf16(a1, bfr, oacc1, 0, 0, 0);
    }
  }
  {
#pragma unroll
    for (int j = 0; j < 4; ++j) {
      int oc = hi2 * 4 + j;
      pypx[oc][pxr] = oacc0[j] + b_off[oc];
    }
    if (hi2 == 0) {
#pragma unroll
      for (int j = 0; j < 2; ++j)
        pypx[16 + j][pxr] = oacc1[j] + b_off[16 + j];
    }
  }
  __syncthreads();

  // ---- phase B: register-direct fragment blend + GEMM, no barriers ----
  v4f acc00 = {0.f, 0.f, 0.f, 0.f};
  v4f acc01 = {0.f, 0.f, 0.f, 0.f};
  v4f acc10 = {0.f, 0.f, 0.f, 0.f};
  v4f acc11 = {0.f, 0.f, 0.f, 0.f};

  const int co0 = (wv & 1) << 5;
  const int px0 = (wv >> 1) << 5;
  const int pr0 = px0 + lo16, pr1 = pr0 + 16;

  for (int kk = 0; kk < 9; ++kk) {
    const int rr = kk / 3, dxk = kk % 3;
    const float byf = (float)(ho - 1 + rr);

    // pixel pr0: weights + position
    float w00a, w01a, w10a, w11a; int yra, xra, y0ia, x0ia; bool insa;
    {
      float dy = pypx[2 * kk][pr0], dxo = pypx[2 * kk + 1][pr0];
      float py  = byf + dy;
      float pxf = (float)(wo0 + pr0 - 1 + dxk) + dxo;
      float y0f = floorf(py), x0f = floorf(pxf);
      float wy1 = py - y0f, wy0 = 1.f - wy1;
      float wx1 = pxf - x0f, wx0 = 1.f - wx1;
      bool vy0 = (y0f >= 0.f)  && (y0f < 128.f);
      bool vy1 = (y0f >= -1.f) && (y0f < 127.f);
      bool vx0 = (x0f >= 0.f)  && (x0f < 128.f);
      bool vx1 = (x0f >= -1.f) && (x0f < 127.f);
      w00a = wy0 * wx0 * ((vy0 && vx0) ? 1.f : 0.f);
      w01a = wy0 * wx1 * ((vy0 && vx1) ? 1.f : 0.f);
      w10a = wy1 * wx0 * ((vy1 && vx0) ? 1.f : 0.f);
      w11a = wy1 * wx1 * ((vy1 && vx1) ? 1.f : 0.f);
      y0ia = (int)y0f; x0ia = (int)x0f;
      yra = y0ia - row0; xra = x0ia - x0s;
      insa = (yra >= 0) && (yra <= 3) && (xra >= 0) && (xra <= 70);
    }
    // pixel pr1
    float w00b, w01b, w10b, w11b; int yrb, xrb, y0ib, x0ib; bool insb;
    {
      float dy = pypx[2 * kk][pr1], dxo = pypx[2 * kk + 1][pr1];
      float py  = byf + dy;
      float pxf = (float)(wo0 + pr1 - 1 + dxk) + dxo;
      float y0f = floorf(py), x0f = floorf(pxf);
      float wy1 = py - y0f, wy0 = 1.f - wy1;
      float wx1 = pxf - x0f, wx0 = 1.f - wx1;
      bool vy0 = (y0f >= 0.f)  && (y0f < 128.f);
      bool vy1 = (y0f >= -1.f) && (y0f < 127.f);
      bool vx0 = (x0f >= 0.f)  && (x0f < 128.f);
      bool vx1 = (x0f >= -1.f) && (x0f < 127.f);
      w00b = wy0 * wx0 * ((vy0 && vx0) ? 1.f : 0.f);
      w01b = wy0 * wx1 * ((vy0 && vx1) ? 1.f : 0.f);
      w10b = wy1 * wx0 * ((vy1 && vx0) ? 1.f : 0.f);
      w11b = wy1 * wx1 * ((vy1 && vx1) ? 1.f : 0.f);
      y0ib = (int)y0f; x0ib = (int)x0f;
      yrb = y0ib - row0; xrb = x0ib - x0s;
      insb = (yrb >= 0) && (yrb <= 3) && (xrb >= 0) && (xrb <= 70);
    }

#pragma unroll
    for (int kst = 0; kst < 2; ++kst) {
      const int k4 = kst * 4 + hi2;
      v8s bh0 = blend_frag(strip, xtb, yra, xra, y0ia, x0ia, k4, insa,
                           w00a, w01a, w10a, w11a);
      v8s bh1 = blend_frag(strip, xtb, yrb, xrb, y0ib, x0ib, k4, insb,
                           w00b, w01b, w10b, w11b);
      const int ko = kk * 64 + kst * 32 + hi2 * 8;
      v8s ah0 = *(const v8s*)(whi + (co0 +      lo16) * 576 + ko);
      v8s al0 = *(const v8s*)(wlo + (co0 +      lo16) * 576 + ko);
      v8s ah1 = *(const v8s*)(whi + (co0 + 16 + lo16) * 576 + ko);
      v8s al1 = *(const v8s*)(wlo + (co0 + 16 + lo16) * 576 + ko);
      acc00 = __builtin_amdgcn_mfma_f32_16x16x32_bf16(ah0, bh0, acc00, 0, 0, 0);
      acc00 = __builtin_amdgcn_mfma_f32_16x16x32_bf16(al0, bh0, acc00, 0, 0, 0);
      acc01 = __builtin_amdgcn_mfma_f32_16x16x32_bf16(ah0, bh1, acc01, 0, 0, 0);
      acc01 = __builtin_amdgcn_mfma_f32_16x16x32_bf16(al0, bh1, acc01, 0, 0, 0);
      acc10 = __builtin_amdgcn_mfma_f32_16x16x32_bf16(ah1, bh0, acc10, 0, 0, 0);
      acc10 = __builtin_amdgcn_mfma_f32_16x16x32_bf16(al1, bh0, acc10, 0, 0, 0);
      acc11 = __builtin_amdgcn_mfma_f32_16x16x32_bf16(ah1, bh1, acc11, 0, 0, 0);
      acc11 = __builtin_amdgcn_mfma_f32_16x16x32_bf16(al1, bh1, acc11, 0, 0, 0);
    }
  }

  // ---- epilogue ----
  const int wo_b = wo0 + px0 + lo16;
#pragma unroll
  for (int j = 0; j < 4; ++j) {
    int coA = co0 + hi2 * 4 + j;
    int coB = co0 + 16 + hi2 * 4 + j;
    out[(((size_t)b * COUT + coA) * Hd + ho) * Wd + wo_b]      = acc00[j];
    out[(((size_t)b * COUT + coA) * Hd + ho) * Wd + wo_b + 16] = acc01[j];
    out[(((size_t)b * COUT + coB) * Hd + ho) * Wd + wo_b]      = acc10[j];
    out[(((size_t)b * COUT + coB) * Hd + ho) * Wd + wo_b + 16] = acc11[j];
  }
}

// =================== fallback (round-3 kernel, NCHW fp32 gathers) ==========
__global__ __launch_bounds__(256, 4) void dconv_old(
    const float* __restrict__ x, const float* __restrict__ b_off,
    const ushort* __restrict__ woff_t, const ushort* __restrict__ whi,
    const ushort* __restrict__ wlo, float* __restrict__ out) {

  __shared__ uint4 colsA[64 * 8];
  __shared__ uint4 colsB[64 * 8];
  __shared__ float pypx[18][64];

  const int t    = threadIdx.x;
  const int lane = t & 63;
  const int wv   = t >> 6;
  const int lo16 = lane & 15, hi2 = lane >> 4;
  const int wid = ((blockIdx.x & 7) << 8) | (blockIdx.x >> 3);
  const int b   = wid >> 8;
  const int ho  = (wid >> 1) & 127;
  const int wo0 = (wid & 1) << 6;
  const int px = t & 63;
  const int g  = t >> 6;
  const float* xb = x + (size_t)b * (CIN * HW);

  v4f oacc0 = {0.f, 0.f, 0.f, 0.f};
  v4f oacc1 = {0.f, 0.f, 0.f, 0.f};

  for (int kk = 0; kk < 9; ++kk) {
    if (kk) __syncthreads();
    {
      int yy = ho - 1 + kk / 3;
      int xx = wo0 + px - 1 + kk % 3;
      bool vok = (yy >= 0) && (yy < Hd) && (xx >= 0) && (xx < Wd);
      const float* xp = xb + (size_t)(g * 16) * HW + yy * Wd + xx;
      uint pk[8];
#pragma unroll
      for (int u = 0; u < 16; u += 2) {
        float a0 = vok ? xp[(u + 0) * HW] : 0.f;
        float a1 = vok ? xp[(u + 1) * HW] : 0.f;
        pk[u >> 1] = f2bf_rn(a0) | (f2bf_rn(a1) << 16);
      }
      uint4 q0 = {pk[0], pk[1], pk[2], pk[3]};
      uint4 q1 = {pk[4], pk[5], pk[6], pk[7]};
      int base = px * 8, s = px & 7;
      colsA[base + ((g * 2 + 0) ^ s)] = q0;
      colsA[base + ((g * 2 + 1) ^ s)] = q1;
    }
    __syncthreads();
    int pxr = wv * 16 + lo16;
#pragma unroll
    for (int kst = 0; kst < 2; ++kst) {
      const v8s* ap0 = (const v8s*)(woff_t + (0  + lo16) * 576 + kk * 64 + kst * 32 + hi2 * 8);
      const v8s* ap1 = (const v8s*)(woff_t + (16 + lo16) * 576 + kk * 64 + kst * 32 + hi2 * 8);
      const v8s* bp  = (const v8s*)&colsA[pxr * 8 + ((kst * 4 + hi2) ^ (pxr & 7))];
      v8s bfr = *bp;
      oacc0 = __builtin_amdgcn_mfma_f32_16x16x32_bf16(*ap0, bfr, oacc0, 0, 0, 0);
      oacc1 = __builtin_amdgcn_mfma_f32_16x16x32_bf16(*ap1, bfr, oacc1, 0, 0, 0);
    }
  }
  {
    int pxw = wv * 16 + lo16;
#pragma unroll
    for (int j = 0; j < 4; ++j) {
      int oc = hi2 * 4 + j;
      pypx[oc][pxw] = oacc0[j] + b_off[oc];
    }
    if (hi2 == 0) {
#pragma unroll
      for (int j = 0; j < 2; ++j)
        pypx[16 + j][pxw] = oacc1[j] + b_off[16 + j];
    }
  }
  __syncthreads();

  v4f acc[2][2];
#pragma unroll
  for (int a = 0; a < 2; ++a)
#pragma unroll
    for (int c = 0; c < 2; ++c) acc[a][c] = (v4f){0.f, 0.f, 0.f, 0.f};

  const int co0 = (wv & 1) << 5;
  const int px0 = (wv >> 1) << 5;

  for (int kk = 0; kk < 9; ++kk) {
    if (kk) __syncthreads();
    {
      float dy = pypx[2 * kk][px], dx = pypx[2 * kk + 1][px];
      float py  = (float)(ho - 1 + kk / 3) + dy;
      float pxf = (float)(wo0 + px - 1 + kk % 3) + dx;
      float y0f = floorf(py), x0f = floorf(pxf);
      float wy1 = py - y0f,  wy0 = 1.f - wy1;
      float wx1 = pxf - x0f, wx0 = 1.f - wx1;
      bool vy0 = (y0f >= 0.f)  && (y0f < (float)Hd);
      bool vy1 = (y0f >= -1.f) && (y0f < (float)(Hd - 1));
      bool vx0 = (x0f >= 0.f)  && (x0f < (float)Wd);
      bool vx1 = (x0f >= -1.f) && (x0f < (float)(Wd - 1));
      float w00 = wy0 * wx0 * ((vy0 && vx0) ? 1.f : 0.f);
      float w01 = wy0 * wx1 * ((vy0 && vx1) ? 1.f : 0.f);
      float w10 = wy1 * wx0 * ((vy1 && vx0) ? 1.f : 0.f);
      float w11 = wy1 * wx1 * ((vy1 && vx1) ? 1.f : 0.f);
      int y0  = (int)fminf(fmaxf(y0f,       0.f), (float)(Hd - 1));
      int y1  = (int)fminf(fmaxf(y0f + 1.f, 0.f), (float)(Hd - 1));
      int x0i = (int)fminf(fmaxf(x0f,       0.f), (float)(Wd - 1));
      int x1i = (int)fminf(fmaxf(x0f + 1.f, 0.f), (float)(Wd - 1));
      const float* xp  = xb + (size_t)(g * 16) * HW;
      const float* p00 = xp + y0 * Wd + x0i;
      const float* p01 = xp + y0 * Wd + x1i;
      const float* p10 = xp + y1 * Wd + x0i;
      const float* p11 = xp + y1 * Wd + x1i;
      uint ph[8], pl[8];
#pragma unroll
      for (int u = 0; u < 16; u += 2) {
        float v0 = w00 * p00[u * HW] + w01 * p01[u * HW] +
                   w10 * p10[u * HW] + w11 * p11[u * HW];
        float v1 = w00 * p00[(u + 1) * HW] + w01 * p01[(u + 1) * HW] +
                   w10 * p10[(u + 1) * HW] + w11 * p11[(u + 1) * HW];
        uint h0, l0, h1, l1;
        split_bf(v0, h0, l0);
        split_bf(v1, h1, l1);
        ph[u >> 1] = h0 | (h1 << 16);
        pl[u >> 1] = l0 | (l1 << 16);
      }
      uint4 qh0 = {ph[0], ph[1], ph[2], ph[3]};
      uint4 qh1 = {ph[4], ph[5], ph[6], ph[7]};
      uint4 ql0 = {pl[0], pl[1], pl[2], pl[3]};
      uint4 ql1 = {pl[4], pl[5], pl[6], pl[7]};
      int base = px * 8, s = px & 7;
      colsA[base + ((g * 2 + 0) ^ s)] = qh0;
      colsA[base + ((g * 2 + 1) ^ s)] = qh1;
      colsB[base + ((g * 2 + 0) ^ s)] = ql0;
      colsB[base + ((g * 2 + 1) ^ s)] = ql1;
    }
    __syncthreads();

#pragma unroll
    for (int kst = 0; kst < 2; ++kst) {
      const int ko = kk * 64 + kst * 32 + hi2 * 8;
      v8s ah0 = *(const v8s*)(whi + (co0 +      lo16) * 576 + ko);
      v8s ah1 = *(const v8s*)(whi + (co0 + 16 + lo16) * 576 + ko);
      v8s al0 = *(const v8s*)(wlo + (co0 +      lo16) * 576 + ko);
      v8s al1 = *(const v8s*)(wlo + (co0 + 16 + lo16) * 576 + ko);
      int pr0 = px0 + lo16, pr1 = px0 + 16 + lo16;
      int k4 = kst * 4 + hi2;
      v8s bh0 = *(const v8s*)&colsA[pr0 * 8 + (k4 ^ (pr0 & 7))];
      v8s bh1 = *(const v8s*)&colsA[pr1 * 8 + (k4 ^ (pr1 & 7))];
      v8s bl0 = *(const v8s*)&colsB[pr0 * 8 + (k4 ^ (pr0 & 7))];
      v8s bl1 = *(const v8s*)&colsB[pr1 * 8 + (k4 ^ (pr1 & 7))];

      acc[0][0] = __builtin_amdgcn_mfma_f32_16x16x32_bf16(ah0, bh0, acc[0][0], 0, 0, 0);
      acc[0][0] = __builtin_amdgcn_mfma_f32_16x16x32_bf16(ah0, bl0, acc[0][0], 0, 0, 0);
      acc[0][0] = __builtin_amdgcn_mfma_f32_16x16x32_bf16(al0, bh0, acc[0][0], 0, 0, 0);
      acc[0][1] = __builtin_amdgcn_mfma_f32_16x16x32_bf16(ah0, bh1, acc[0][1], 0, 0, 0);
      acc[0][1] = __builtin_amdgcn_mfma_f32_16x16x32_bf16(ah0, bl1, acc[0][1], 0, 0, 0);
      acc[0][1] = __builtin_amdgcn_mfma_f32_16x16x32_bf16(al0, bh1, acc[0][1], 0, 0, 0);
      acc[1][0] = __builtin_amdgcn_mfma_f32_16x16x32_bf16(ah1, bh0, acc[1][0], 0, 0, 0);
      acc[1][0] = __builtin_amdgcn_mfma_f32_16x16x32_bf16(ah1, bl0, acc[1][0], 0, 0, 0);
      acc[1][0] = __builtin_amdgcn_mfma_f32_16x16x32_bf16(al1, bh0, acc[1][0], 0, 0, 0);
      acc[1][1] = __builtin_amdgcn_mfma_f32_16x16x32_bf16(ah1, bh1, acc[1][1], 0, 0, 0);
      acc[1][1] = __builtin_amdgcn_mfma_f32_16x16x32_bf16(ah1, bl1, acc[1][1], 0, 0, 0);
      acc[1][1] = __builtin_amdgcn_mfma_f32_16x16x32_bf16(al1, bh1, acc[1][1], 0, 0, 0);
    }
  }

  const int wo_b = wo0 + px0 + lo16;
#pragma unroll
  for (int ct = 0; ct < 2; ++ct) {
#pragma unroll
    for (int pt = 0; pt < 2; ++pt) {
#pragma unroll
      for (int j = 0; j < 4; ++j) {
        int co = co0 + ct * 16 + hi2 * 4 + j;
        out[(((size_t)b * COUT + co) * Hd + ho) * Wd + wo_b + pt * 16] = acc[ct][pt][j];
      }
    }
  }
}

extern "C" void kernel_launch(void* const* d_in, const int* in_sizes, int n_in,
                              void* d_out, int out_size, void* d_ws, size_t ws_size,
                              hipStream_t stream) {
  const float* x     = (const float*)d_in[0];
  const float* w_off = (const float*)d_in[1];
  const float* b_off = (const float*)d_in[2];
  const float* w     = (const float*)d_in[3];
  float* out = (float*)d_out;

  const size_t XT_ELT = (size_t)8 * HW * CIN;          // 8,388,608 ushorts
  const size_t NEED   = XT_ELT * 2 + 2u * (18432 + 36864 + 36864);

  ushort* base = (ushort*)d_ws;
  ushort *x_t, *woff_t, *whi, *wlo;
  bool fast = (ws_size >= NEED);
  if (fast) {
    x_t    = base;
    woff_t = base + XT_ELT;
  } else {
    x_t    = nullptr;
    woff_t = base;
  }
  whi = woff_t + 18432;
  wlo = whi + 36864;

  repack<<<144, 256, 0, stream>>>(w_off, w, woff_t, whi, wlo);

  if (fast) {
    transpose_nhwc<<<8 * Hd, 256, 0, stream>>>(x, x_t);
    dconv4<<<2048, 256, 0, stream>>>(x_t, b_off, woff_t, whi, wlo, out);
  } else {
    dconv_old<<<2048, 256, 0, stream>>>(x, b_off, woff_t, whi, wlo, out);
  }
}